// Round 10
// baseline (449.872 us; speedup 1.0000x reference)
//
#include <hip/hip_runtime.h>
#include <hip/hip_bf16.h>

#define NV 100000
#define EPSB 1e-5f
#define FB 256      // fused-kernel grid (1 block/CU, all co-resident)
#define BVOX 392    // voxels per fused block (256*392 >= NV, mult of 4)

typedef unsigned short u16;
typedef unsigned int u32;
typedef _Float16 hv2 __attribute__((ext_vector_type(2)));

__device__ __forceinline__ u32 pkh(float x, float y) {
  auto h = __builtin_amdgcn_cvt_pkrtz(x, y);
  union { decltype(h) v; u32 u; } c; c.v = h; return c.u;
}
__device__ __forceinline__ float fdot2(u32 w, u32 x, float acc) {
#if __has_builtin(__builtin_amdgcn_fdot2)
  union { u32 u; hv2 h; } a, b; a.u = w; b.u = x;
  return __builtin_amdgcn_fdot2(a.h, b.h, acc, false);
#else
  union { u32 u; hv2 h; } a, b; a.u = w; b.u = x;
  return acc + (float)a.h.x*(float)b.h.x + (float)a.h.y*(float)b.h.y;
#endif
}
__device__ __forceinline__ u32 bcastu(u32 v, int l) {
  return (u32)__builtin_amdgcn_readlane((int)v, l);
}
__device__ __forceinline__ hv2 as_hv(u32 u) {
  union { u32 u; hv2 h; } c; c.u = u; return c.h;
}
__device__ __forceinline__ u32 as_u32h(hv2 h) {
  union { hv2 h; u32 u; } c; c.h = h; return c.u;
}
__device__ __forceinline__ hv2 hmax2v(hv2 a, hv2 b) {
#if __has_builtin(__builtin_elementwise_max)
  return __builtin_elementwise_max(a, b);
#else
  hv2 r; r.x = a.x > b.x ? a.x : b.x; r.y = a.y > b.y ? a.y : b.y; return r;
#endif
}
__device__ __forceinline__ hv2 hfma2v(hv2 a, hv2 b, hv2 c) {
#if __has_builtin(__builtin_elementwise_fma)
  return __builtin_elementwise_fma(a, b, c);
#else
  return a * b + c;
#endif
}
__device__ __forceinline__ u16 f2h(float x) { return (u16)(pkh(x, x) & 0xffffu); }
__device__ __forceinline__ float h2f(u16 u) {
  union { u16 u; _Float16 h; } c; c.u = u; return (float)c.h;
}

// ---------------------------------------------------------------------------
// K0: detect key_mask element width (int32 vs byte-bool).
// ---------------------------------------------------------------------------
__global__ void k0_detect(const u32* __restrict__ km, int* __restrict__ flag) {
  int bad = 0;
  for (int i = threadIdx.x; i < 4096; i += 256) {
    u32 v = km[i];
    bad |= (v != 0u && v != 1u && v != 0x3F800000u) ? 1 : 0;
  }
  unsigned long long m = __ballot(bad != 0);
  __shared__ int sbad[4];
  if ((threadIdx.x & 63) == 0) sbad[threadIdx.x >> 6] = (m != 0ull);
  __syncthreads();
  if (threadIdx.x == 0) flag[0] = !(sbad[0] | sbad[1] | sbad[2] | sbad[3]);
}

// ---------------------------------------------------------------------------
// Kprep: VP[m][cp] = { pkh(vf pair), pkh(P pair) }  (frozen, round 8)
// ---------------------------------------------------------------------------
__global__ __launch_bounds__(256) void k_prep(
    const float* __restrict__ vf, const float* __restrict__ coords,
    const float* __restrict__ kpw, u32* __restrict__ VP)
{
  const int t = blockIdx.x*256 + threadIdx.x;
  const int cp = t & 31;
  const float wa0 = kpw[(2*cp)*3],   wa1 = kpw[(2*cp)*3+1],   wa2 = kpw[(2*cp)*3+2];
  const float wb0 = kpw[(2*cp+1)*3], wb1 = kpw[(2*cp+1)*3+1], wb2 = kpw[(2*cp+1)*3+2];
  for (int e = t; e < NV*32; e += 524288) {
    const int m = e >> 5;
    const float2 v2 = *(const float2*)&vf[(u32)m*64u + 2u*(u32)cp];
    const float c0 = coords[m*3], c1 = coords[m*3+1], c2 = coords[m*3+2];
    const float P0 = fmaf(wa0, c0, fmaf(wa1, c1, wa2*c2));
    const float P1 = fmaf(wb0, c0, fmaf(wb1, c1, wb2*c2));
    uint2 o; o.x = pkh(v2.x, v2.y); o.y = pkh(P0, P1);
    *(uint2*)&VP[(u32)e*2u] = o;
  }
}

// ---------------------------------------------------------------------------
// K1: gather attention (frozen, round 9 — 226us, mixed VALU/LDS bound).
// ---------------------------------------------------------------------------
__global__ __launch_bounds__(512, 4) void k1_attn(
    const float* __restrict__ vf, const float* __restrict__ coords,
    const int* __restrict__ kidx, const void* __restrict__ kmaskv,
    const int* __restrict__ mflag, const u32* __restrict__ VP,
    const float* __restrict__ wq, const float* __restrict__ bq,
    const float* __restrict__ wk,
    const float* __restrict__ wv, const float* __restrict__ bv,
    const float* __restrict__ wo, const float* __restrict__ bo,
    const float* __restrict__ qpw, const float* __restrict__ qpb,
    const float* __restrict__ kpb,
    float* __restrict__ x1pre, float* __restrict__ stats)
{
  extern __shared__ char smem[];
  u32* WQP = (u32*)smem;
  u32* WKP = WQP + 2048;
  u32* WVP = WKP + 2048;
  u32* WOP = WVP + 2048;
  const int tid = threadIdx.x, wid = tid >> 6, lane = tid & 63;

  for (int t = tid; t < 2048; t += 512) {
    int cp = t >> 6, i = t & 63;
    WQP[t] = pkh(wq[i*64 + 2*cp], wq[i*64 + 2*cp + 1]);
    WKP[t] = pkh(wk[(2*cp)*64 + i], wk[(2*cp+1)*64 + i]);
    WVP[t] = pkh(wv[i*64 + 2*cp], wv[i*64 + 2*cp + 1]);
    WOP[t] = pkh(wo[i*64 + 2*cp], wo[i*64 + 2*cp + 1]);
  }
  __syncthreads();

  u32* wbase = (u32*)(smem + 32768) + wid * 1320;
  u32* KFp = wbase;
  u32* QKp = wbase + 1056;
  u32* SP  = wbase + 1188;

  const int cl = lane & 31, kh = lane >> 5, hp = lane >> 5, hh = lane >> 4;
  const int ca = 2*cl;
  const float qp0 = qpw[lane*3], qp1 = qpw[lane*3+1], qp2 = qpw[lane*3+2], qpbl = qpb[lane];
  const hv2 kpbp = as_hv(pkh(kpb[ca], kpb[ca+1]));
  const hv2 z2 = (hv2)(_Float16)0;
  const float bql = bq[lane], bvl = bv[lane], bol = bo[lane];
  const int mode4 = mflag[0];
  const u32* km32 = (const u32*)kmaskv;
  const unsigned char* km8 = (const unsigned char*)kmaskv;
  float ssum = 0.f, ssq = 0.f;

  for (int n = blockIdx.x*8 + wid; n < NV; n += 4096) {
    const float cn0 = coords[n*3], cn1 = coords[n*3+1], cn2 = coords[n*3+2];
    u32 mk;
    if (mode4) mk = (km32[n*32 + cl] != 0u);
    else       mk = (km8[n*32 + cl]  != 0u);
    const float vfl = vf[(u32)n*64u + (u32)lane];
    const uint2 wn = *(const uint2*)&VP[(u32)n*64u + (u32)ca];
    const hv2 pnp = as_hv(wn.y) - kpbp;

    union { int4 v[4]; int s[16]; } iu;
    {
      const int4* kp4 = (const int4*)(kidx + (u32)n*32u + (u32)(kh*16));
      iu.v[0] = kp4[0]; iu.v[1] = kp4[1]; iu.v[2] = kp4[2]; iu.v[3] = kp4[3];
    }

    #pragma unroll
    for (int b = 0; b < 2; ++b) {
      uint2 g[8];
      #pragma unroll
      for (int k = 0; k < 8; ++k) {
        const u32 off = ((u32)iu.s[b*8+k] << 6) + (u32)ca;
        g[k] = *(const uint2*)&VP[off];
      }
      #pragma unroll
      for (int k = 0; k < 8; ++k) {
        hv2 pe = hmax2v(as_hv(g[k].y) - pnp, z2);
        KFp[(kh*16 + b*8 + k)*33 + cl] = as_u32h(as_hv(g[k].x) + pe);
      }
    }

    float query = vfl + fmaxf(fmaf(qp0,cn0,fmaf(qp1,cn1,fmaf(qp2,cn2,qpbl))), 0.f);
    const u32 qpk = pkh(query, __shfl_down(query, 1));

    float qa0 = bql, qa1 = 0.f;
    #pragma unroll
    for (int cp = 0; cp < 16; ++cp) {
      qa0 = fdot2(WQP[ cp    *64 + lane], bcastu(qpk, 2*cp     ), qa0);
      qa1 = fdot2(WQP[(cp+16)*64 + lane], bcastu(qpk, 2*cp + 32), qa1);
    }
    const float qacc = (qa0 + qa1) * 0.25f;
    const u32 qpk2 = pkh(qacc, __shfl_down(qacc, 1));

    float qkh0=0.f, qkh1=0.f, qkh2=0.f, qkh3=0.f;
    #pragma unroll
    for (int p = 0; p < 8; ++p) {
      qkh0 = fdot2(WKP[( p    )*64+lane], bcastu(qpk2, 2*p     ), qkh0);
      qkh1 = fdot2(WKP[( p+ 8 )*64+lane], bcastu(qpk2, 2*p + 16), qkh1);
      qkh2 = fdot2(WKP[( p+16 )*64+lane], bcastu(qpk2, 2*p + 32), qkh2);
      qkh3 = fdot2(WKP[( p+24 )*64+lane], bcastu(qpk2, 2*p + 48), qkh3);
    }
    {
      float t0 = __shfl_down(qkh0, 1), t1 = __shfl_down(qkh1, 1);
      float t2 = __shfl_down(qkh2, 1), t3 = __shfl_down(qkh3, 1);
      if ((lane & 1) == 0) {
        int j = lane >> 1;
        QKp[      j] = pkh(qkh0, t0);
        QKp[ 33 + j] = pkh(qkh1, t1);
        QKp[ 66 + j] = pkh(qkh2, t2);
        QKp[ 99 + j] = pkh(qkh3, t3);
      }
    }

    float s00=0.f, s01=0.f, s10=0.f, s11=0.f;
    #pragma unroll
    for (int cp = 0; cp < 16; ++cp) {
      u32 kpa  = KFp[cl*33 + cp];
      u32 kpb2 = KFp[cl*33 + cp + 16];
      s00 = fdot2(kpa,  QKp[(2*hp  )*33 + cp     ], s00);
      s01 = fdot2(kpb2, QKp[(2*hp  )*33 + cp + 16], s01);
      s10 = fdot2(kpa,  QKp[(2*hp+1)*33 + cp     ], s10);
      s11 = fdot2(kpb2, QKp[(2*hp+1)*33 + cp + 16], s11);
    }
    float sc0 = s00 + s01, sc1 = s10 + s11;
    if (mk) { sc0 = -1e30f; sc1 = -1e30f; }

    float m0 = sc0, m1 = sc1;
    #pragma unroll
    for (int off = 16; off; off >>= 1) {
      m0 = fmaxf(m0, __shfl_xor(m0, off));
      m1 = fmaxf(m1, __shfl_xor(m1, off));
    }
    float p0 = __expf(sc0 - m0), p1 = __expf(sc1 - m1);
    float s0 = p0, s1 = p1;
    #pragma unroll
    for (int off = 16; off; off >>= 1) {
      s0 += __shfl_xor(s0, off);
      s1 += __shfl_xor(s1, off);
    }
    const float a0 = p0 / s0, a1 = p1 / s1;

    u32* APlo = QKp;
    u32* APhi = QKp + 66;
    APlo[lane] = pkh(a0, a0);
    APhi[lane] = pkh(a1, a1);

    const int j = lane & 31;
    const int ab = hp << 5;
    hv2 accA = z2, accB = z2;
    #pragma unroll
    for (int k2 = 0; k2 < 32; ++k2) {
      hv2 kf = as_hv(KFp[k2*33 + j]);
      accA = hfma2v(kf, as_hv(APlo[ab + k2]), accA);
      accB = hfma2v(kf, as_hv(APhi[ab + k2]), accB);
    }
    SP[(2*hp  )*33 + j] = as_u32h(accA);
    SP[(2*hp+1)*33 + j] = as_u32h(accB);

    float ca0 = bvl, ca1 = 0.f;
    #pragma unroll
    for (int cp = 0; cp < 16; ++cp) {
      ca0 = fdot2(WVP[ cp    *64 + lane], SP[hh*33 + cp     ], ca0);
      ca1 = fdot2(WVP[(cp+16)*64 + lane], SP[hh*33 + cp + 16], ca1);
    }
    const float cacc = ca0 + ca1;
    const u32 cpk = pkh(cacc, __shfl_down(cacc, 1));

    float oa0 = bol, oa1 = 0.f;
    #pragma unroll
    for (int cp = 0; cp < 16; ++cp) {
      oa0 = fdot2(WOP[ cp    *64 + lane], bcastu(cpk, 2*cp     ), oa0);
      oa1 = fdot2(WOP[(cp+16)*64 + lane], bcastu(cpk, 2*cp + 32), oa1);
    }
    const float aacc = oa0 + oa1;

    float x1 = vfl + aacc;
    x1pre[(u32)n*64u + (u32)lane] = x1;
    ssum += x1; ssq = fmaf(x1, x1, ssq);
  }

  __syncthreads();
  float* red = (float*)smem;
  red[wid*64 + lane] = ssum;
  red[512 + wid*64 + lane] = ssq;
  __syncthreads();
  if (wid == 0) {
    float t1 = 0.f, t2 = 0.f;
    #pragma unroll
    for (int w = 0; w < 8; ++w) { t1 += red[w*64+lane]; t2 += red[512+w*64+lane]; }
    atomicAdd(&stats[lane], t1);
    atomicAdd(&stats[64+lane], t2);
  }
}

// ---------------------------------------------------------------------------
// K345: fused BN1+FFN -> BN2+out-proj -> BN3+ReLU with device-wide spin
// barriers.  256 blocks x 512 thr, 1 block/CU (121KB LDS) -> all co-resident.
// x2 / outpre live in block-local LDS as f16 (each wave touches only its own
// voxels).  Eliminates x2pre/outpre HBM round-trips + 2 launches.
// ---------------------------------------------------------------------------
__global__ __launch_bounds__(512) void k345(
    const float* __restrict__ x1pre, float* __restrict__ stats,
    int* __restrict__ bars,
    const float* __restrict__ g1, const float* __restrict__ b1,
    const float* __restrict__ l1w, const float* __restrict__ l1b,
    const float* __restrict__ l2w, const float* __restrict__ l2b,
    const float* __restrict__ g2, const float* __restrict__ b2,
    const float* __restrict__ outw, const float* __restrict__ outb,
    const float* __restrict__ g3, const float* __restrict__ b3,
    float* __restrict__ out)
{
  extern __shared__ char smem[];
  u32* L1P = (u32*)smem;            // [cp][f] f16 pairs, 32KB
  u32* L2P = L1P + 8192;            // [fp][c] f16 pairs, 32KB
  u32* WTP = L2P + 8192;            // [cp][o] f16 pairs, 8KB
  u16* X2  = (u16*)(WTP + 2048);    // [BVOX][64] f16, 50176B
  const int tid = threadIdx.x, wid = tid >> 6, lane = tid & 63;

  for (int t = tid; t < 8192; t += 512) {
    int cp = t >> 8, f = t & 255;
    L1P[t] = pkh(l1w[f*64 + 2*cp], l1w[f*64 + 2*cp + 1]);
  }
  for (int t = tid; t < 8192; t += 512) {
    int fp = t >> 6, c = t & 63;
    float2 w2 = *(const float2*)&l2w[c*256 + 2*fp];
    L2P[t] = pkh(w2.x, w2.y);
  }
  for (int t = tid; t < 2048; t += 512) {
    int cp = t >> 6, o = t & 63;
    WTP[t] = pkh(outw[o*64 + 2*cp], outw[o*64 + 2*cp + 1]);
  }
  __syncthreads();

  const int base = blockIdx.x * BVOX;
  const int nvb  = min(NV - base, BVOX);   // > 0 for all 256 blocks; mult of 4

  // ---- stage 1: BN1 + FFN -> X2 (f16, LDS) + BN2 partials ----
  {
    const float mean = stats[lane] * (1.f/NV);
    const float var  = stats[64+lane] * (1.f/NV) - mean*mean;
    const float sc   = rsqrtf(var + EPSB) * g1[lane];
    const float sh   = b1[lane] - mean * sc;
    const float4 l1b4 = *(const float4*)&l1b[4*lane];
    const float l2bl = l2b[lane];
    float ssum = 0.f, ssq = 0.f;

    for (int i0 = wid*4; i0 < nvb; i0 += 32) {
      const int n0 = base + i0;
      float xa = x1pre[(size_t) n0   *64+lane] * sc + sh;
      float xb = x1pre[(size_t)(n0+1)*64+lane] * sc + sh;
      float xc = x1pre[(size_t)(n0+2)*64+lane] * sc + sh;
      float xd = x1pre[(size_t)(n0+3)*64+lane] * sc + sh;
      const u32 xpa = pkh(xa, __shfl_down(xa,1));
      const u32 xpb = pkh(xb, __shfl_down(xb,1));
      const u32 xpc = pkh(xc, __shfl_down(xc,1));
      const u32 xpd = pkh(xd, __shfl_down(xd,1));

      float h00=l1b4.x, h01=l1b4.y, h02=l1b4.z, h03=l1b4.w;
      float h10=l1b4.x, h11=l1b4.y, h12=l1b4.z, h13=l1b4.w;
      float h20=l1b4.x, h21=l1b4.y, h22=l1b4.z, h23=l1b4.w;
      float h30=l1b4.x, h31=l1b4.y, h32=l1b4.z, h33=l1b4.w;
      #pragma unroll 8
      for (int cp = 0; cp < 32; ++cp) {
        uint4 w = *(const uint4*)&L1P[cp*256 + 4*lane];
        u32 x0 = bcastu(xpa, 2*cp), x1 = bcastu(xpb, 2*cp);
        u32 x2 = bcastu(xpc, 2*cp), x3 = bcastu(xpd, 2*cp);
        h00=fdot2(w.x,x0,h00); h01=fdot2(w.y,x0,h01); h02=fdot2(w.z,x0,h02); h03=fdot2(w.w,x0,h03);
        h10=fdot2(w.x,x1,h10); h11=fdot2(w.y,x1,h11); h12=fdot2(w.z,x1,h12); h13=fdot2(w.w,x1,h13);
        h20=fdot2(w.x,x2,h20); h21=fdot2(w.y,x2,h21); h22=fdot2(w.z,x2,h22); h23=fdot2(w.w,x2,h23);
        h30=fdot2(w.x,x3,h30); h31=fdot2(w.y,x3,h31); h32=fdot2(w.z,x3,h32); h33=fdot2(w.w,x3,h33);
      }
      h00=fmaxf(h00,0.f); h01=fmaxf(h01,0.f); h02=fmaxf(h02,0.f); h03=fmaxf(h03,0.f);
      h10=fmaxf(h10,0.f); h11=fmaxf(h11,0.f); h12=fmaxf(h12,0.f); h13=fmaxf(h13,0.f);
      h20=fmaxf(h20,0.f); h21=fmaxf(h21,0.f); h22=fmaxf(h22,0.f); h23=fmaxf(h23,0.f);
      h30=fmaxf(h30,0.f); h31=fmaxf(h31,0.f); h32=fmaxf(h32,0.f); h33=fmaxf(h33,0.f);

      const u32 hpa0 = pkh(h00,h01), hpa1 = pkh(h02,h03);
      const u32 hpb0 = pkh(h10,h11), hpb1 = pkh(h12,h13);
      const u32 hpc0 = pkh(h20,h21), hpc1 = pkh(h22,h23);
      const u32 hpd0 = pkh(h30,h31), hpd1 = pkh(h32,h33);

      float f0 = l2bl, f1 = l2bl, f2v = l2bl, f3 = l2bl;
      #pragma unroll 8
      for (int i = 0; i < 64; ++i) {
        u32 w0 = L2P[(2*i  )*64 + lane];
        u32 w1 = L2P[(2*i+1)*64 + lane];
        f0  = fdot2(w0, bcastu(hpa0, i), f0);  f0  = fdot2(w1, bcastu(hpa1, i), f0);
        f1  = fdot2(w0, bcastu(hpb0, i), f1);  f1  = fdot2(w1, bcastu(hpb1, i), f1);
        f2v = fdot2(w0, bcastu(hpc0, i), f2v); f2v = fdot2(w1, bcastu(hpc1, i), f2v);
        f3  = fdot2(w0, bcastu(hpd0, i), f3);  f3  = fdot2(w1, bcastu(hpd1, i), f3);
      }

      float y0 = xa + f0, y1 = xb + f1, y2 = xc + f2v, y3 = xd + f3;
      X2[(i0+0)*64 + lane] = f2h(y0);
      X2[(i0+1)*64 + lane] = f2h(y1);
      X2[(i0+2)*64 + lane] = f2h(y2);
      X2[(i0+3)*64 + lane] = f2h(y3);
      ssum += (y0 + y1) + (y2 + y3);
      ssq = fmaf(y0,y0, fmaf(y1,y1, fmaf(y2,y2, fmaf(y3,y3, ssq))));
    }

    // block-reduce BN2 partials (red aliases L1P? NO — L1P needed in... L1P
    // is dead after stage 1; use a small dedicated slice at end of X2 region
    // is unsafe; reduce via global atomics per wave instead: shuffle-free,
    // 8 atomics per channel per block are cheap (256 blocks * 8 = 2048/chan).
    atomicAdd(&stats[128+lane], ssum);
    atomicAdd(&stats[192+lane], ssq);
  }

  // ---- device-wide barrier 1 ----
  __syncthreads();
  if (tid == 0) {
    __threadfence();
    atomicAdd(&bars[0], 1);
    while (__hip_atomic_load(&bars[0], __ATOMIC_ACQUIRE, __HIP_MEMORY_SCOPE_AGENT) < FB)
      __builtin_amdgcn_s_sleep(1);
  }
  __syncthreads();

  // ---- stage 2: BN2 + out-proj -> X2 (overwrite, f16) + BN3 partials ----
  {
    const float m2 = __hip_atomic_load(&stats[128+lane], __ATOMIC_RELAXED, __HIP_MEMORY_SCOPE_AGENT) * (1.f/NV);
    const float q2 = __hip_atomic_load(&stats[192+lane], __ATOMIC_RELAXED, __HIP_MEMORY_SCOPE_AGENT) * (1.f/NV);
    const float var  = q2 - m2*m2;
    const float sc   = rsqrtf(var + EPSB) * g2[lane];
    const float sh   = b2[lane] - m2 * sc;
    const float obl  = outb[lane];
    float ssum = 0.f, ssq = 0.f;

    for (int i0 = wid*4; i0 < nvb; i0 += 32) {
      float xa = h2f(X2[(i0+0)*64+lane]) * sc + sh;
      float xb = h2f(X2[(i0+1)*64+lane]) * sc + sh;
      float xc = h2f(X2[(i0+2)*64+lane]) * sc + sh;
      float xd = h2f(X2[(i0+3)*64+lane]) * sc + sh;
      const u32 xpa = pkh(xa, __shfl_down(xa,1));
      const u32 xpb = pkh(xb, __shfl_down(xb,1));
      const u32 xpc = pkh(xc, __shfl_down(xc,1));
      const u32 xpd = pkh(xd, __shfl_down(xd,1));
      float a0 = obl, a1 = obl, a2 = obl, a3 = obl;
      #pragma unroll 8
      for (int cp = 0; cp < 32; ++cp) {
        u32 w = WTP[cp*64 + lane];
        a0 = fdot2(w, bcastu(xpa, 2*cp), a0);
        a1 = fdot2(w, bcastu(xpb, 2*cp), a1);
        a2 = fdot2(w, bcastu(xpc, 2*cp), a2);
        a3 = fdot2(w, bcastu(xpd, 2*cp), a3);
      }
      X2[(i0+0)*64+lane] = f2h(a0);
      X2[(i0+1)*64+lane] = f2h(a1);
      X2[(i0+2)*64+lane] = f2h(a2);
      X2[(i0+3)*64+lane] = f2h(a3);
      ssum += (a0 + a1) + (a2 + a3);
      ssq = fmaf(a0,a0, fmaf(a1,a1, fmaf(a2,a2, fmaf(a3,a3, ssq))));
    }

    atomicAdd(&stats[256+lane], ssum);
    atomicAdd(&stats[320+lane], ssq);
  }

  // ---- device-wide barrier 2 ----
  __syncthreads();
  if (tid == 0) {
    __threadfence();
    atomicAdd(&bars[1], 1);
    while (__hip_atomic_load(&bars[1], __ATOMIC_ACQUIRE, __HIP_MEMORY_SCOPE_AGENT) < FB)
      __builtin_amdgcn_s_sleep(1);
  }
  __syncthreads();

  // ---- stage 3: BN3 + ReLU -> out ----
  {
    const float m3 = __hip_atomic_load(&stats[256+lane], __ATOMIC_RELAXED, __HIP_MEMORY_SCOPE_AGENT) * (1.f/NV);
    const float q3 = __hip_atomic_load(&stats[320+lane], __ATOMIC_RELAXED, __HIP_MEMORY_SCOPE_AGENT) * (1.f/NV);
    const float var = q3 - m3*m3;
    const float sc  = rsqrtf(var + EPSB) * g3[lane];
    const float sh  = b3[lane] - m3 * sc;
    for (int i0 = wid*4; i0 < nvb; i0 += 32) {
      const int n0 = base + i0;
      #pragma unroll
      for (int v = 0; v < 4; ++v) {
        float val = h2f(X2[(i0+v)*64+lane]);
        out[(size_t)(n0+v)*64 + lane] = fmaxf(fmaf(val, sc, sh), 0.f);
      }
    }
  }
}

extern "C" void kernel_launch(void* const* d_in, const int* in_sizes, int n_in,
                              void* d_out, int out_size, void* d_ws, size_t ws_size,
                              hipStream_t stream) {
  (void)in_sizes; (void)n_in; (void)out_size; (void)ws_size;
  const float* vf     = (const float*)d_in[0];
  const float* coords = (const float*)d_in[1];
  const int*   kidx   = (const int*)d_in[2];
  const void*  kmask  = d_in[3];
  const float* wq  = (const float*)d_in[4];  const float* bq  = (const float*)d_in[5];
  const float* wk  = (const float*)d_in[6];  /* bk cancels in softmax */
  const float* wv  = (const float*)d_in[8];  const float* bv  = (const float*)d_in[9];
  const float* wo  = (const float*)d_in[10]; const float* bo  = (const float*)d_in[11];
  const float* qpw = (const float*)d_in[12]; const float* qpb = (const float*)d_in[13];
  const float* kpw = (const float*)d_in[14]; const float* kpb = (const float*)d_in[15];
  const float* g1  = (const float*)d_in[16]; const float* b1  = (const float*)d_in[17];
  const float* g2  = (const float*)d_in[18]; const float* b2  = (const float*)d_in[19];
  const float* l1w = (const float*)d_in[20]; const float* l1b = (const float*)d_in[21];
  const float* l2w = (const float*)d_in[22]; const float* l2b = (const float*)d_in[23];
  const float* outw= (const float*)d_in[24]; const float* outb= (const float*)d_in[25];
  const float* g3  = (const float*)d_in[26]; const float* b3  = (const float*)d_in[27];

  float* wsf    = (float*)d_ws;
  float* x1pre  = wsf;                       // [N*64]
  float* scratch= wsf + (size_t)NV*64;       // [N*64]; VP table (dead after K1)
  u32*   VP     = (u32*)scratch;
  float* stats  = wsf + (size_t)2*NV*64;     // [384]
  int*   bars   = (int*)(stats + 384);       // [2] spin-barrier counters
  int*   mflag  = (int*)(stats + 388);

  // zero stats + barrier counters each launch (captured in graph -> per replay)
  (void)hipMemsetAsync(stats, 0, 388*sizeof(float), stream);

  (void)hipFuncSetAttribute((const void*)k1_attn, hipFuncAttributeMaxDynamicSharedMemorySize, 75008);
  (void)hipFuncSetAttribute((const void*)k345,    hipFuncAttributeMaxDynamicSharedMemorySize, 123904);

  k0_detect<<<1, 256, 0, stream>>>((const u32*)kmask, mflag);
  k_prep<<<2048, 256, 0, stream>>>(vf, coords, kpw, VP);
  k1_attn<<<512, 512, 75008, stream>>>(vf, coords, kidx, kmask, mflag, VP,
      wq, bq, wk, wv, bv, wo, bo, qpw, qpb, kpb, x1pre, stats);
  k345<<<FB, 512, 123904, stream>>>(x1pre, stats, bars,
      g1, b1, l1w, l1b, l2w, l2b, g2, b2, outw, outb, g3, b3, (float*)d_out);
}

// Round 11
// 308.636 us; speedup vs baseline: 1.4576x; 1.4576x over previous
//
#include <hip/hip_runtime.h>
#include <hip/hip_bf16.h>

#define NV 100000
#define EPSB 1e-5f

typedef unsigned short u16;
typedef unsigned int u32;
typedef _Float16 hv2 __attribute__((ext_vector_type(2)));
typedef _Float16 h8  __attribute__((ext_vector_type(8)));
typedef float f32x4  __attribute__((ext_vector_type(4)));

__device__ __forceinline__ u32 pkh(float x, float y) {
  auto h = __builtin_amdgcn_cvt_pkrtz(x, y);
  union { decltype(h) v; u32 u; } c; c.v = h; return c.u;
}
__device__ __forceinline__ float fdot2(u32 w, u32 x, float acc) {
#if __has_builtin(__builtin_amdgcn_fdot2)
  union { u32 u; hv2 h; } a, b; a.u = w; b.u = x;
  return __builtin_amdgcn_fdot2(a.h, b.h, acc, false);
#else
  union { u32 u; hv2 h; } a, b; a.u = w; b.u = x;
  return acc + (float)a.h.x*(float)b.h.x + (float)a.h.y*(float)b.h.y;
#endif
}
__device__ __forceinline__ u32 bcastu(u32 v, int l) {
  return (u32)__builtin_amdgcn_readlane((int)v, l);
}
__device__ __forceinline__ hv2 as_hv(u32 u) {
  union { u32 u; hv2 h; } c; c.u = u; return c.h;
}
__device__ __forceinline__ u32 as_u32h(hv2 h) {
  union { hv2 h; u32 u; } c; c.h = h; return c.u;
}
__device__ __forceinline__ hv2 hmax2v(hv2 a, hv2 b) {
#if __has_builtin(__builtin_elementwise_max)
  return __builtin_elementwise_max(a, b);
#else
  hv2 r; r.x = a.x > b.x ? a.x : b.x; r.y = a.y > b.y ? a.y : b.y; return r;
#endif
}
__device__ __forceinline__ hv2 hfma2v(hv2 a, hv2 b, hv2 c) {
#if __has_builtin(__builtin_elementwise_fma)
  return __builtin_elementwise_fma(a, b, c);
#else
  return a * b + c;
#endif
}
__device__ __forceinline__ u16 f2h(float x) { return (u16)(pkh(x, x) & 0xffffu); }
__device__ __forceinline__ float h2f(u16 u) {
  union { u16 u; _Float16 h; } c; c.u = u; return (float)c.h;
}
__device__ __forceinline__ f32x4 mfma16(h8 a, h8 b, f32x4 c) {
  return __builtin_amdgcn_mfma_f32_16x16x32_f16(a, b, c, 0, 0, 0);
}

// ---------------------------------------------------------------------------
// K0: detect key_mask element width (int32 vs byte-bool).
// ---------------------------------------------------------------------------
__global__ void k0_detect(const u32* __restrict__ km, int* __restrict__ flag) {
  int bad = 0;
  for (int i = threadIdx.x; i < 4096; i += 256) {
    u32 v = km[i];
    bad |= (v != 0u && v != 1u && v != 0x3F800000u) ? 1 : 0;
  }
  unsigned long long m = __ballot(bad != 0);
  __shared__ int sbad[4];
  if ((threadIdx.x & 63) == 0) sbad[threadIdx.x >> 6] = (m != 0ull);
  __syncthreads();
  if (threadIdx.x == 0) flag[0] = !(sbad[0] | sbad[1] | sbad[2] | sbad[3]);
}

// ---------------------------------------------------------------------------
// Kprep: VP[m][cp] = { pkh(vf pair), pkh(P pair) }  (frozen, round 8)
// ---------------------------------------------------------------------------
__global__ __launch_bounds__(256) void k_prep(
    const float* __restrict__ vf, const float* __restrict__ coords,
    const float* __restrict__ kpw, u32* __restrict__ VP)
{
  const int t = blockIdx.x*256 + threadIdx.x;
  const int cp = t & 31;
  const float wa0 = kpw[(2*cp)*3],   wa1 = kpw[(2*cp)*3+1],   wa2 = kpw[(2*cp)*3+2];
  const float wb0 = kpw[(2*cp+1)*3], wb1 = kpw[(2*cp+1)*3+1], wb2 = kpw[(2*cp+1)*3+2];
  for (int e = t; e < NV*32; e += 524288) {
    const int m = e >> 5;
    const float2 v2 = *(const float2*)&vf[(u32)m*64u + 2u*(u32)cp];
    const float c0 = coords[m*3], c1 = coords[m*3+1], c2 = coords[m*3+2];
    const float P0 = fmaf(wa0, c0, fmaf(wa1, c1, wa2*c2));
    const float P1 = fmaf(wb0, c0, fmaf(wb1, c1, wb2*c2));
    uint2 o; o.x = pkh(v2.x, v2.y); o.y = pkh(P0, P1);
    *(uint2*)&VP[(u32)e*2u] = o;
  }
}

// ---------------------------------------------------------------------------
// K1: gather attention (frozen, round 9 — 226us).
// ---------------------------------------------------------------------------
__global__ __launch_bounds__(512, 4) void k1_attn(
    const float* __restrict__ vf, const float* __restrict__ coords,
    const int* __restrict__ kidx, const void* __restrict__ kmaskv,
    const int* __restrict__ mflag, const u32* __restrict__ VP,
    const float* __restrict__ wq, const float* __restrict__ bq,
    const float* __restrict__ wk,
    const float* __restrict__ wv, const float* __restrict__ bv,
    const float* __restrict__ wo, const float* __restrict__ bo,
    const float* __restrict__ qpw, const float* __restrict__ qpb,
    const float* __restrict__ kpb,
    float* __restrict__ x1pre, float* __restrict__ stats)
{
  extern __shared__ char smem[];
  u32* WQP = (u32*)smem;
  u32* WKP = WQP + 2048;
  u32* WVP = WKP + 2048;
  u32* WOP = WVP + 2048;
  const int tid = threadIdx.x, wid = tid >> 6, lane = tid & 63;

  for (int t = tid; t < 2048; t += 512) {
    int cp = t >> 6, i = t & 63;
    WQP[t] = pkh(wq[i*64 + 2*cp], wq[i*64 + 2*cp + 1]);
    WKP[t] = pkh(wk[(2*cp)*64 + i], wk[(2*cp+1)*64 + i]);
    WVP[t] = pkh(wv[i*64 + 2*cp], wv[i*64 + 2*cp + 1]);
    WOP[t] = pkh(wo[i*64 + 2*cp], wo[i*64 + 2*cp + 1]);
  }
  __syncthreads();

  u32* wbase = (u32*)(smem + 32768) + wid * 1320;
  u32* KFp = wbase;
  u32* QKp = wbase + 1056;
  u32* SP  = wbase + 1188;

  const int cl = lane & 31, kh = lane >> 5, hp = lane >> 5, hh = lane >> 4;
  const int ca = 2*cl;
  const float qp0 = qpw[lane*3], qp1 = qpw[lane*3+1], qp2 = qpw[lane*3+2], qpbl = qpb[lane];
  const hv2 kpbp = as_hv(pkh(kpb[ca], kpb[ca+1]));
  const hv2 z2 = (hv2)(_Float16)0;
  const float bql = bq[lane], bvl = bv[lane], bol = bo[lane];
  const int mode4 = mflag[0];
  const u32* km32 = (const u32*)kmaskv;
  const unsigned char* km8 = (const unsigned char*)kmaskv;
  float ssum = 0.f, ssq = 0.f;

  for (int n = blockIdx.x*8 + wid; n < NV; n += 4096) {
    const float cn0 = coords[n*3], cn1 = coords[n*3+1], cn2 = coords[n*3+2];
    u32 mk;
    if (mode4) mk = (km32[n*32 + cl] != 0u);
    else       mk = (km8[n*32 + cl]  != 0u);
    const float vfl = vf[(u32)n*64u + (u32)lane];
    const uint2 wn = *(const uint2*)&VP[(u32)n*64u + (u32)ca];
    const hv2 pnp = as_hv(wn.y) - kpbp;

    union { int4 v[4]; int s[16]; } iu;
    {
      const int4* kp4 = (const int4*)(kidx + (u32)n*32u + (u32)(kh*16));
      iu.v[0] = kp4[0]; iu.v[1] = kp4[1]; iu.v[2] = kp4[2]; iu.v[3] = kp4[3];
    }

    #pragma unroll
    for (int b = 0; b < 2; ++b) {
      uint2 g[8];
      #pragma unroll
      for (int k = 0; k < 8; ++k) {
        const u32 off = ((u32)iu.s[b*8+k] << 6) + (u32)ca;
        g[k] = *(const uint2*)&VP[off];
      }
      #pragma unroll
      for (int k = 0; k < 8; ++k) {
        hv2 pe = hmax2v(as_hv(g[k].y) - pnp, z2);
        KFp[(kh*16 + b*8 + k)*33 + cl] = as_u32h(as_hv(g[k].x) + pe);
      }
    }

    float query = vfl + fmaxf(fmaf(qp0,cn0,fmaf(qp1,cn1,fmaf(qp2,cn2,qpbl))), 0.f);
    const u32 qpk = pkh(query, __shfl_down(query, 1));

    float qa0 = bql, qa1 = 0.f;
    #pragma unroll
    for (int cp = 0; cp < 16; ++cp) {
      qa0 = fdot2(WQP[ cp    *64 + lane], bcastu(qpk, 2*cp     ), qa0);
      qa1 = fdot2(WQP[(cp+16)*64 + lane], bcastu(qpk, 2*cp + 32), qa1);
    }
    const float qacc = (qa0 + qa1) * 0.25f;
    const u32 qpk2 = pkh(qacc, __shfl_down(qacc, 1));

    float qkh0=0.f, qkh1=0.f, qkh2=0.f, qkh3=0.f;
    #pragma unroll
    for (int p = 0; p < 8; ++p) {
      qkh0 = fdot2(WKP[( p    )*64+lane], bcastu(qpk2, 2*p     ), qkh0);
      qkh1 = fdot2(WKP[( p+ 8 )*64+lane], bcastu(qpk2, 2*p + 16), qkh1);
      qkh2 = fdot2(WKP[( p+16 )*64+lane], bcastu(qpk2, 2*p + 32), qkh2);
      qkh3 = fdot2(WKP[( p+24 )*64+lane], bcastu(qpk2, 2*p + 48), qkh3);
    }
    {
      float t0 = __shfl_down(qkh0, 1), t1 = __shfl_down(qkh1, 1);
      float t2 = __shfl_down(qkh2, 1), t3 = __shfl_down(qkh3, 1);
      if ((lane & 1) == 0) {
        int j = lane >> 1;
        QKp[      j] = pkh(qkh0, t0);
        QKp[ 33 + j] = pkh(qkh1, t1);
        QKp[ 66 + j] = pkh(qkh2, t2);
        QKp[ 99 + j] = pkh(qkh3, t3);
      }
    }

    float s00=0.f, s01=0.f, s10=0.f, s11=0.f;
    #pragma unroll
    for (int cp = 0; cp < 16; ++cp) {
      u32 kpa  = KFp[cl*33 + cp];
      u32 kpb2 = KFp[cl*33 + cp + 16];
      s00 = fdot2(kpa,  QKp[(2*hp  )*33 + cp     ], s00);
      s01 = fdot2(kpb2, QKp[(2*hp  )*33 + cp + 16], s01);
      s10 = fdot2(kpa,  QKp[(2*hp+1)*33 + cp     ], s10);
      s11 = fdot2(kpb2, QKp[(2*hp+1)*33 + cp + 16], s11);
    }
    float sc0 = s00 + s01, sc1 = s10 + s11;
    if (mk) { sc0 = -1e30f; sc1 = -1e30f; }

    float m0 = sc0, m1 = sc1;
    #pragma unroll
    for (int off = 16; off; off >>= 1) {
      m0 = fmaxf(m0, __shfl_xor(m0, off));
      m1 = fmaxf(m1, __shfl_xor(m1, off));
    }
    float p0 = __expf(sc0 - m0), p1 = __expf(sc1 - m1);
    float s0 = p0, s1 = p1;
    #pragma unroll
    for (int off = 16; off; off >>= 1) {
      s0 += __shfl_xor(s0, off);
      s1 += __shfl_xor(s1, off);
    }
    const float a0 = p0 / s0, a1 = p1 / s1;

    u32* APlo = QKp;
    u32* APhi = QKp + 66;
    APlo[lane] = pkh(a0, a0);
    APhi[lane] = pkh(a1, a1);

    const int j = lane & 31;
    const int ab = hp << 5;
    hv2 accA = z2, accB = z2;
    #pragma unroll
    for (int k2 = 0; k2 < 32; ++k2) {
      hv2 kf = as_hv(KFp[k2*33 + j]);
      accA = hfma2v(kf, as_hv(APlo[ab + k2]), accA);
      accB = hfma2v(kf, as_hv(APhi[ab + k2]), accB);
    }
    SP[(2*hp  )*33 + j] = as_u32h(accA);
    SP[(2*hp+1)*33 + j] = as_u32h(accB);

    float ca0 = bvl, ca1 = 0.f;
    #pragma unroll
    for (int cp = 0; cp < 16; ++cp) {
      ca0 = fdot2(WVP[ cp    *64 + lane], SP[hh*33 + cp     ], ca0);
      ca1 = fdot2(WVP[(cp+16)*64 + lane], SP[hh*33 + cp + 16], ca1);
    }
    const float cacc = ca0 + ca1;
    const u32 cpk = pkh(cacc, __shfl_down(cacc, 1));

    float oa0 = bol, oa1 = 0.f;
    #pragma unroll
    for (int cp = 0; cp < 16; ++cp) {
      oa0 = fdot2(WOP[ cp    *64 + lane], bcastu(cpk, 2*cp     ), oa0);
      oa1 = fdot2(WOP[(cp+16)*64 + lane], bcastu(cpk, 2*cp + 32), oa1);
    }
    const float aacc = oa0 + oa1;

    float x1 = vfl + aacc;
    x1pre[(u32)n*64u + (u32)lane] = x1;
    ssum += x1; ssq = fmaf(x1, x1, ssq);
  }

  __syncthreads();
  float* red = (float*)smem;
  red[wid*64 + lane] = ssum;
  red[512 + wid*64 + lane] = ssq;
  __syncthreads();
  if (wid == 0) {
    float t1 = 0.f, t2 = 0.f;
    #pragma unroll
    for (int w = 0; w < 8; ++w) { t1 += red[w*64+lane]; t2 += red[512+w*64+lane]; }
    atomicAdd(&stats[lane], t1);
    atomicAdd(&stats[64+lane], t2);
  }
}

// ---------------------------------------------------------------------------
// K3 (MFMA): x2pre = x1 + FFN(BN1(x1pre)); BN2 partials.
// 256 blocks x 512 thr (8 waves), 64-voxel tiles. GEMM1 [64x64]x[64x256],
// GEMM2 [64x256]x[256x64] via mfma_f32_16x16x32_f16. Weights pre-staged in
// B-fragment order (k-contiguous per (col, lane-group) -> conflict-free b128).
// A/B k-ordering is self-consistent (operand symmetry makes any bijective
// k-map valid); C/D mapping col=lane&15,row=(lane>>4)*4+reg (HW-verified).
// LDS 110848B -> 1 block/CU. Tail tile masked at store/stats.
// ---------------------------------------------------------------------------
__global__ __launch_bounds__(512) void k3_mfma(
    const float* __restrict__ x1pre, float* __restrict__ stats,
    const float* __restrict__ g1, const float* __restrict__ b1,
    const float* __restrict__ l1w, const float* __restrict__ l1b,
    const float* __restrict__ l2w, const float* __restrict__ l2b,
    float* __restrict__ x2pre)
{
  extern __shared__ char smem[];
  u32*   W1B  = (u32*)smem;                 // [n16][kk2][g4][col16][j2x4] 32KB
  u32*   W2B  = W1B + 8192;                 // [n4][kk8][g4][col16][j2x4] 32KB
  u16*   XA   = (u16*)(W2B + 8192);         // [64][72] f16 (BN1'd x1)  9216B
  u16*   H    = XA + 4608;                  // [64][264] f16 hidden     33792B
  float* l1bs = (float*)(H + 16896);        // [256]
  float* l2bs = l1bs + 256;                 // [64]
  float* scb  = l2bs + 64;                  // [64]
  float* shb  = scb + 64;                   // [64]
  float* red  = shb + 64;                   // [128] BN2 partials
  const int tid = threadIdx.x, wid = tid >> 6, lane = tid & 63;

  // stage W1B: u32 idx e = ((n*2+kk)*4+g)*64 + col*4 + j2
  for (int e = tid; e < 8192; e += 512) {
    int j2 = e & 3, col = (e>>2) & 15, g = (e>>6) & 3, kk = (e>>8) & 1, n = e >> 9;
    int f = 16*n + col, k = kk*32 + g*8 + 2*j2;
    W1B[e] = pkh(l1w[f*64 + k], l1w[f*64 + k + 1]);
  }
  // stage W2B: u32 idx e = ((n*8+kk)*4+g)*64 + col*4 + j2
  for (int e = tid; e < 8192; e += 512) {
    int j2 = e & 3, col = (e>>2) & 15, g = (e>>6) & 3, kk = (e>>8) & 7, n = e >> 11;
    int c = 16*n + col, k = kk*32 + g*8 + 2*j2;
    W2B[e] = pkh(l2w[c*256 + k], l2w[c*256 + k + 1]);
  }
  if (tid < 256) l1bs[tid] = l1b[tid];
  if (tid < 64)  l2bs[tid] = l2b[tid];
  if (tid < 64) {
    float mean = stats[tid] * (1.f/NV);
    float var  = stats[64+tid] * (1.f/NV) - mean*mean;
    float sc = rsqrtf(var + EPSB) * g1[tid];
    scb[tid] = sc;
    shb[tid] = b1[tid] - mean * sc;
  }
  if (tid < 128) red[tid] = 0.f;

  const int m  = wid & 3;     // m-tile for this wave
  const int wh = wid >> 2;    // work-half (0/1)
  const int lg = lane >> 4, ll = lane & 15;
  float ss0 = 0.f, sq0 = 0.f, ss1 = 0.f, sq1 = 0.f;

  for (int tile = blockIdx.x; tile < 1563; tile += 256) {
    const int base = tile * 64;
    __syncthreads();   // protect XA/H from previous iteration's readers
    // ---- stage XA: BN1(x1pre tile) -> f16 ----
    {
      int row = tid >> 3, cq = (tid & 7) * 8;
      int srow = base + row; if (srow >= NV) srow = NV - 1;
      const float* src = x1pre + (size_t)srow*64 + cq;
      u32* dst = (u32*)XA + row*36 + (tid & 7)*4;
      #pragma unroll
      for (int q = 0; q < 4; ++q) {
        float v0 = src[2*q]   * scb[cq+2*q]   + shb[cq+2*q];
        float v1 = src[2*q+1] * scb[cq+2*q+1] + shb[cq+2*q+1];
        dst[q] = pkh(v0, v1);
      }
    }
    __syncthreads();
    // ---- GEMM1: H[64][256] = relu(XA x W1 + b1); wave: m, n = 8*wh..+8 ----
    {
      const u16* arow = XA + (16*m + ll)*72 + lg*8;
      h8 a0 = *(const h8*)(arow);
      h8 a1 = *(const h8*)(arow + 32);
      #pragma unroll
      for (int nn = 0; nn < 8; ++nn) {
        int n = 8*wh + nn;
        const u32* bb = W1B + (n*8 + lg)*64 + ll*4;   // (n*2+0)*4+g
        h8 b0 = *(const h8*)(bb);
        h8 b1v = *(const h8*)(bb + 256);               // kk=1
        f32x4 acc = {0.f, 0.f, 0.f, 0.f};
        acc = mfma16(a0, b0, acc);
        acc = mfma16(a1, b1v, acc);
        float bias = l1bs[16*n + ll];
        u16* hw = H + (16*m + lg*4)*264 + 16*n + ll;
        #pragma unroll
        for (int r = 0; r < 4; ++r)
          hw[r*264] = f2h(fmaxf(acc[r] + bias, 0.f));
      }
    }
    __syncthreads();
    // ---- GEMM2: y = H x W2 + b2 + x1; wave: m, n in {2*wh, 2*wh+1} ----
    {
      const u16* arow = H + (16*m + ll)*264 + lg*8;
      h8 a[8];
      #pragma unroll
      for (int kk = 0; kk < 8; ++kk) a[kk] = *(const h8*)(arow + kk*32);
      #pragma unroll
      for (int nn = 0; nn < 2; ++nn) {
        int n = 2*wh + nn;
        const u32* bb = W2B + (n*32 + lg)*64 + ll*4;  // (n*8+0)*4+g
        f32x4 acA = {0.f,0.f,0.f,0.f}, acB = {0.f,0.f,0.f,0.f};
        #pragma unroll
        for (int kk = 0; kk < 8; kk += 2) {
          h8 b0 = *(const h8*)(bb + kk*256);
          h8 b1v = *(const h8*)(bb + (kk+1)*256);
          acA = mfma16(a[kk],   b0,  acA);
          acB = mfma16(a[kk+1], b1v, acB);
        }
        const int col = 16*n + ll;
        const float bias = l2bs[col];
        const u16* xr = XA + (16*m + lg*4)*72 + col;
        const int vox0 = base + 16*m + lg*4;
        float ss = 0.f, sq = 0.f;
        #pragma unroll
        for (int r = 0; r < 4; ++r) {
          int vox = vox0 + r;
          if (vox < NV) {
            float y = acA[r] + acB[r] + bias + h2f(xr[r*72]);
            x2pre[(size_t)vox*64 + col] = y;
            ss += y; sq = fmaf(y, y, sq);
          }
        }
        if (nn == 0) { ss0 += ss; sq0 += sq; } else { ss1 += ss; sq1 += sq; }
      }
    }
  }

  // ---- BN2 partials: LDS-atomic reduce then one global atomic per channel ----
  __syncthreads();
  const int c2a = 16*(2*wh)     + ll;
  const int c2b = 16*(2*wh + 1) + ll;
  atomicAdd(&red[c2a], ss0);
  atomicAdd(&red[64 + c2a], sq0);
  atomicAdd(&red[c2b], ss1);
  atomicAdd(&red[64 + c2b], sq1);
  __syncthreads();
  if (tid < 64) {
    atomicAdd(&stats[128+tid], red[tid]);
    atomicAdd(&stats[192+tid], red[64+tid]);
  }
}

// ---------------------------------------------------------------------------
// K4: x2 = BN2(x2pre); outpre = x2 @ out_w^T + out_b; BN3 partials. (round 9)
// ---------------------------------------------------------------------------
__global__ __launch_bounds__(256) void k4_out(
    const float* __restrict__ x2pre, float* __restrict__ stats,
    const float* __restrict__ g2, const float* __restrict__ b2,
    const float* __restrict__ outw, const float* __restrict__ outb,
    float* __restrict__ outpre)
{
  extern __shared__ char smem[];
  u32* WTP = (u32*)smem;                      // [cp][o] f16 pairs, 8KB
  const int tid = threadIdx.x, wid = tid >> 6, lane = tid & 63;
  for (int t = tid; t < 2048; t += 256) {
    int cp = t >> 6, o = t & 63;
    WTP[t] = pkh(outw[o*64 + 2*cp], outw[o*64 + 2*cp + 1]);
  }
  __syncthreads();

  const float mean = stats[128+lane] * (1.f/NV);
  const float var  = stats[192+lane] * (1.f/NV) - mean*mean;
  const float sc   = rsqrtf(var + EPSB) * g2[lane];
  const float sh   = b2[lane] - mean * sc;
  const float obl  = outb[lane];
  float ssum = 0.f, ssq = 0.f;

  const int stride = gridDim.x << 4;
  for (int n0 = blockIdx.x*16 + wid*4; n0 < NV; n0 += stride) {
    float xa = x2pre[(size_t) n0   *64+lane] * sc + sh;
    float xb = x2pre[(size_t)(n0+1)*64+lane] * sc + sh;
    float xc = x2pre[(size_t)(n0+2)*64+lane] * sc + sh;
    float xd = x2pre[(size_t)(n0+3)*64+lane] * sc + sh;
    const u32 xpa = pkh(xa, __shfl_down(xa,1));
    const u32 xpb = pkh(xb, __shfl_down(xb,1));
    const u32 xpc = pkh(xc, __shfl_down(xc,1));
    const u32 xpd = pkh(xd, __shfl_down(xd,1));
    float a0 = obl, a1 = obl, a2 = obl, a3 = obl;
    #pragma unroll 8
    for (int cp = 0; cp < 32; ++cp) {
      u32 w = WTP[cp*64 + lane];
      a0 = fdot2(w, bcastu(xpa, 2*cp), a0);
      a1 = fdot2(w, bcastu(xpb, 2*cp), a1);
      a2 = fdot2(w, bcastu(xpc, 2*cp), a2);
      a3 = fdot2(w, bcastu(xpd, 2*cp), a3);
    }
    outpre[(size_t) n0   *64+lane] = a0;
    outpre[(size_t)(n0+1)*64+lane] = a1;
    outpre[(size_t)(n0+2)*64+lane] = a2;
    outpre[(size_t)(n0+3)*64+lane] = a3;
    ssum += (a0 + a1) + (a2 + a3);
    ssq = fmaf(a0,a0, fmaf(a1,a1, fmaf(a2,a2, fmaf(a3,a3, ssq))));
  }

  __syncthreads();
  float* red = (float*)smem;
  red[wid*64+lane] = ssum;
  red[256 + wid*64 + lane] = ssq;
  __syncthreads();
  if (wid == 0) {
    float t1 = 0.f, t2 = 0.f;
    #pragma unroll
    for (int w = 0; w < 4; ++w) { t1 += red[w*64+lane]; t2 += red[256+w*64+lane]; }
    atomicAdd(&stats[256+lane], t1);
    atomicAdd(&stats[320+lane], t2);
  }
}

// ---------------------------------------------------------------------------
// K5: out = relu(BN3(outpre))  (round 9)
// ---------------------------------------------------------------------------
__global__ __launch_bounds__(256) void k5_fin(
    const float* __restrict__ outpre, const float* __restrict__ stats,
    const float* __restrict__ g3, const float* __restrict__ b3,
    float* __restrict__ out)
{
  const int t = blockIdx.x*256 + threadIdx.x;
  const int c0 = (t*4) & 63;
  float sc[4], sh[4];
  #pragma unroll
  for (int j = 0; j < 4; ++j) {
    int c = c0 + j;
    float mean = stats[256+c] * (1.f/NV);
    float var  = stats[320+c] * (1.f/NV) - mean*mean;
    sc[j] = rsqrtf(var + EPSB) * g3[c];
    sh[j] = b3[c] - mean*sc[j];
  }
  for (int i = t; i < NV*16; i += 131072) {
    float4 v = *(const float4*)&outpre[(size_t)i*4];
    v.x = fmaxf(fmaf(v.x, sc[0], sh[0]), 0.f);
    v.y = fmaxf(fmaf(v.y, sc[1], sh[1]), 0.f);
    v.z = fmaxf(fmaf(v.z, sc[2], sh[2]), 0.f);
    v.w = fmaxf(fmaf(v.w, sc[3], sh[3]), 0.f);
    *(float4*)&out[(size_t)i*4] = v;
  }
}

extern "C" void kernel_launch(void* const* d_in, const int* in_sizes, int n_in,
                              void* d_out, int out_size, void* d_ws, size_t ws_size,
                              hipStream_t stream) {
  (void)in_sizes; (void)n_in; (void)out_size; (void)ws_size;
  const float* vf     = (const float*)d_in[0];
  const float* coords = (const float*)d_in[1];
  const int*   kidx   = (const int*)d_in[2];
  const void*  kmask  = d_in[3];
  const float* wq  = (const float*)d_in[4];  const float* bq  = (const float*)d_in[5];
  const float* wk  = (const float*)d_in[6];  /* bk cancels in softmax */
  const float* wv  = (const float*)d_in[8];  const float* bv  = (const float*)d_in[9];
  const float* wo  = (const float*)d_in[10]; const float* bo  = (const float*)d_in[11];
  const float* qpw = (const float*)d_in[12]; const float* qpb = (const float*)d_in[13];
  const float* kpw = (const float*)d_in[14]; const float* kpb = (const float*)d_in[15];
  const float* g1  = (const float*)d_in[16]; const float* b1  = (const float*)d_in[17];
  const float* g2  = (const float*)d_in[18]; const float* b2  = (const float*)d_in[19];
  const float* l1w = (const float*)d_in[20]; const float* l1b = (const float*)d_in[21];
  const float* l2w = (const float*)d_in[22]; const float* l2b = (const float*)d_in[23];
  const float* outw= (const float*)d_in[24]; const float* outb= (const float*)d_in[25];
  const float* g3  = (const float*)d_in[26]; const float* b3  = (const float*)d_in[27];

  float* wsf    = (float*)d_ws;
  float* x1pre  = wsf;                       // [N*64]
  float* x2pre  = wsf + (size_t)NV*64;       // [N*64]; aliases VP before K3
  u32*   VP     = (u32*)x2pre;               // packed (vf,P) f16 table, dead after K1
  float* outpre = x1pre;                     // alias: x1pre dead after K3
  float* stats  = wsf + (size_t)2*NV*64;     // [384]
  int*   mflag  = (int*)(stats + 384);

  (void)hipMemsetAsync(stats, 0, 384*sizeof(float), stream);

  (void)hipFuncSetAttribute((const void*)k1_attn, hipFuncAttributeMaxDynamicSharedMemorySize, 75008);
  (void)hipFuncSetAttribute((const void*)k3_mfma, hipFuncAttributeMaxDynamicSharedMemorySize, 110848);

  k0_detect<<<1, 256, 0, stream>>>((const u32*)kmask, mflag);
  k_prep<<<2048, 256, 0, stream>>>(vf, coords, kpw, VP);
  k1_attn<<<512, 512, 75008, stream>>>(vf, coords, kidx, kmask, mflag, VP,
      wq, bq, wk, wv, bv, wo, bo, qpw, qpb, kpb, x1pre, stats);
  k3_mfma<<<256, 512, 110848, stream>>>(x1pre, stats, g1, b1, l1w, l1b, l2w, l2b, x2pre);
  k4_out<<<1024, 256, 8192, stream>>>(x2pre, stats, g2, b2, outw, outb, outpre);
  k5_fin<<<512, 256, 0, stream>>>(outpre, stats, g3, b3, (float*)d_out);
}

// Round 12
// 304.085 us; speedup vs baseline: 1.4794x; 1.0150x over previous
//
#include <hip/hip_runtime.h>
#include <hip/hip_bf16.h>

#define NV 100000
#define EPSB 1e-5f

typedef unsigned short u16;
typedef unsigned int u32;
typedef _Float16 hv2 __attribute__((ext_vector_type(2)));
typedef _Float16 h8  __attribute__((ext_vector_type(8)));
typedef float f32x4  __attribute__((ext_vector_type(4)));

__device__ __forceinline__ u32 pkh(float x, float y) {
  auto h = __builtin_amdgcn_cvt_pkrtz(x, y);
  union { decltype(h) v; u32 u; } c; c.v = h; return c.u;
}
__device__ __forceinline__ float fdot2(u32 w, u32 x, float acc) {
#if __has_builtin(__builtin_amdgcn_fdot2)
  union { u32 u; hv2 h; } a, b; a.u = w; b.u = x;
  return __builtin_amdgcn_fdot2(a.h, b.h, acc, false);
#else
  union { u32 u; hv2 h; } a, b; a.u = w; b.u = x;
  return acc + (float)a.h.x*(float)b.h.x + (float)a.h.y*(float)b.h.y;
#endif
}
__device__ __forceinline__ u32 bcastu(u32 v, int l) {
  return (u32)__builtin_amdgcn_readlane((int)v, l);
}
__device__ __forceinline__ hv2 as_hv(u32 u) {
  union { u32 u; hv2 h; } c; c.u = u; return c.h;
}
__device__ __forceinline__ u32 as_u32h(hv2 h) {
  union { hv2 h; u32 u; } c; c.h = h; return c.u;
}
__device__ __forceinline__ hv2 hmax2v(hv2 a, hv2 b) {
#if __has_builtin(__builtin_elementwise_max)
  return __builtin_elementwise_max(a, b);
#else
  hv2 r; r.x = a.x > b.x ? a.x : b.x; r.y = a.y > b.y ? a.y : b.y; return r;
#endif
}
__device__ __forceinline__ hv2 hfma2v(hv2 a, hv2 b, hv2 c) {
#if __has_builtin(__builtin_elementwise_fma)
  return __builtin_elementwise_fma(a, b, c);
#else
  return a * b + c;
#endif
}
__device__ __forceinline__ u16 f2h(float x) { return (u16)(pkh(x, x) & 0xffffu); }
__device__ __forceinline__ float h2f(u16 u) {
  union { u16 u; _Float16 h; } c; c.u = u; return (float)c.h;
}
__device__ __forceinline__ f32x4 mfma16(h8 a, h8 b, f32x4 c) {
  return __builtin_amdgcn_mfma_f32_16x16x32_f16(a, b, c, 0, 0, 0);
}

// ---------------------------------------------------------------------------
// K0: detect key_mask element width (int32 vs byte-bool).
// ---------------------------------------------------------------------------
__global__ void k0_detect(const u32* __restrict__ km, int* __restrict__ flag) {
  int bad = 0;
  for (int i = threadIdx.x; i < 4096; i += 256) {
    u32 v = km[i];
    bad |= (v != 0u && v != 1u && v != 0x3F800000u) ? 1 : 0;
  }
  unsigned long long m = __ballot(bad != 0);
  __shared__ int sbad[4];
  if ((threadIdx.x & 63) == 0) sbad[threadIdx.x >> 6] = (m != 0ull);
  __syncthreads();
  if (threadIdx.x == 0) flag[0] = !(sbad[0] | sbad[1] | sbad[2] | sbad[3]);
}

// ---------------------------------------------------------------------------
// Kprep: VP[m][cp] = { pkh(vf pair), pkh(P pair) }  (frozen, round 8)
// ---------------------------------------------------------------------------
__global__ __launch_bounds__(256) void k_prep(
    const float* __restrict__ vf, const float* __restrict__ coords,
    const float* __restrict__ kpw, u32* __restrict__ VP)
{
  const int t = blockIdx.x*256 + threadIdx.x;
  const int cp = t & 31;
  const float wa0 = kpw[(2*cp)*3],   wa1 = kpw[(2*cp)*3+1],   wa2 = kpw[(2*cp)*3+2];
  const float wb0 = kpw[(2*cp+1)*3], wb1 = kpw[(2*cp+1)*3+1], wb2 = kpw[(2*cp+1)*3+2];
  for (int e = t; e < NV*32; e += 524288) {
    const int m = e >> 5;
    const float2 v2 = *(const float2*)&vf[(u32)m*64u + 2u*(u32)cp];
    const float c0 = coords[m*3], c1 = coords[m*3+1], c2 = coords[m*3+2];
    const float P0 = fmaf(wa0, c0, fmaf(wa1, c1, wa2*c2));
    const float P1 = fmaf(wb0, c0, fmaf(wb1, c1, wb2*c2));
    uint2 o; o.x = pkh(v2.x, v2.y); o.y = pkh(P0, P1);
    *(uint2*)&VP[(u32)e*2u] = o;
  }
}

// ---------------------------------------------------------------------------
// K1: gather attention.  Round-12: all paired LDS traffic widened to b64
// (weights as uint2{cp,cp+16}, QKH2 [hp][cp]={h2hp,h2hp+1}, API2 attn pairs,
// SPP interleaved {cp,cp+16}; KFp pitch 34 for b64 alignment).  Math is
// bit-identical to round 9; only LDS layout/issue-width changed.
// Scratch/wave 5440B -> LDS 76288B, 2 blocks/CU.
// ---------------------------------------------------------------------------
__global__ __launch_bounds__(512, 4) void k1_attn(
    const float* __restrict__ vf, const float* __restrict__ coords,
    const int* __restrict__ kidx, const void* __restrict__ kmaskv,
    const int* __restrict__ mflag, const u32* __restrict__ VP,
    const float* __restrict__ wq, const float* __restrict__ bq,
    const float* __restrict__ wk,
    const float* __restrict__ wv, const float* __restrict__ bv,
    const float* __restrict__ wo, const float* __restrict__ bo,
    const float* __restrict__ qpw, const float* __restrict__ qpb,
    const float* __restrict__ kpb,
    float* __restrict__ x1pre, float* __restrict__ stats)
{
  extern __shared__ char smem[];
  uint2* WQP2 = (uint2*)smem;        // [cp 0..15][i]: {wq cp, wq cp+16} 8KB
  uint2* WKP2 = WQP2 + 1024;         // [p 0..15][c]: p<8 {p,p+8} else {p+8,p+16}
  uint2* WVP2 = WKP2 + 1024;
  uint2* WOP2 = WVP2 + 1024;
  const int tid = threadIdx.x, wid = tid >> 6, lane = tid & 63;

  for (int t = tid; t < 1024; t += 512) {
    int cp = t >> 6, i = t & 63;
    uint2 v;
    v.x = pkh(wq[i*64 + 2*cp],      wq[i*64 + 2*cp + 1]);
    v.y = pkh(wq[i*64 + 2*cp + 32], wq[i*64 + 2*cp + 33]);
    WQP2[t] = v;
    int lo = (cp < 8) ? cp : cp + 8, hi = lo + 8;
    v.x = pkh(wk[2*lo*64 + i], wk[(2*lo+1)*64 + i]);
    v.y = pkh(wk[2*hi*64 + i], wk[(2*hi+1)*64 + i]);
    WKP2[t] = v;
    v.x = pkh(wv[i*64 + 2*cp],      wv[i*64 + 2*cp + 1]);
    v.y = pkh(wv[i*64 + 2*cp + 32], wv[i*64 + 2*cp + 33]);
    WVP2[t] = v;
    v.x = pkh(wo[i*64 + 2*cp],      wo[i*64 + 2*cp + 1]);
    v.y = pkh(wo[i*64 + 2*cp + 32], wo[i*64 + 2*cp + 33]);
    WOP2[t] = v;
  }
  __syncthreads();

  u32* wbase = (u32*)(smem + 32768) + wid * 1360;
  u32*   KFp  = wbase;                    // [32 keys][34] f16 c-pairs (pitch 34)
  uint2* QKH2 = (uint2*)(wbase + 1088);   // [hp][cp 0..31]: {head 2hp, 2hp+1}
  uint2* API2 = QKH2;                     // alias: attn pairs after scores
  u32*   SPP  = wbase + 1216;             // [4 heads][34]: interleave {cp, cp+16}

  const int cl = lane & 31, kh = lane >> 5, hp = lane >> 5, hh = lane >> 4;
  const int ca = 2*cl;
  const float qp0 = qpw[lane*3], qp1 = qpw[lane*3+1], qp2 = qpw[lane*3+2], qpbl = qpb[lane];
  const hv2 kpbp = as_hv(pkh(kpb[ca], kpb[ca+1]));
  const hv2 z2 = (hv2)(_Float16)0;
  const float bql = bq[lane], bvl = bv[lane], bol = bo[lane];
  const int mode4 = mflag[0];
  const u32* km32 = (const u32*)kmaskv;
  const unsigned char* km8 = (const unsigned char*)kmaskv;
  float ssum = 0.f, ssq = 0.f;

  for (int n = blockIdx.x*8 + wid; n < NV; n += 4096) {
    const float cn0 = coords[n*3], cn1 = coords[n*3+1], cn2 = coords[n*3+2];
    u32 mk;
    if (mode4) mk = (km32[n*32 + cl] != 0u);
    else       mk = (km8[n*32 + cl]  != 0u);
    const float vfl = vf[(u32)n*64u + (u32)lane];
    const uint2 wn = *(const uint2*)&VP[(u32)n*64u + (u32)ca];
    const hv2 pnp = as_hv(wn.y) - kpbp;

    union { int4 v[4]; int s[16]; } iu;
    {
      const int4* kp4 = (const int4*)(kidx + (u32)n*32u + (u32)(kh*16));
      iu.v[0] = kp4[0]; iu.v[1] = kp4[1]; iu.v[2] = kp4[2]; iu.v[3] = kp4[3];
    }

    // ---- gather packed (vf,P) + pos-emb -> KFp (pitch 34) ----
    #pragma unroll
    for (int b = 0; b < 2; ++b) {
      uint2 g[8];
      #pragma unroll
      for (int k = 0; k < 8; ++k) {
        const u32 off = ((u32)iu.s[b*8+k] << 6) + (u32)ca;
        g[k] = *(const uint2*)&VP[off];
      }
      #pragma unroll
      for (int k = 0; k < 8; ++k) {
        hv2 pe = hmax2v(as_hv(g[k].y) - pnp, z2);
        KFp[(kh*16 + b*8 + k)*34 + cl] = as_u32h(as_hv(g[k].x) + pe);
      }
    }

    // ---- query = vf + relu(coords @ qpw^T + qpb); pack pairs ----
    float query = vfl + fmaxf(fmaf(qp0,cn0,fmaf(qp1,cn1,fmaf(qp2,cn2,qpbl))), 0.f);
    const u32 qpk = pkh(query, __shfl_down(query, 1));

    // ---- q[i] = Wq query + bq (lane = i), dot2, b64 weights ----
    float qa0 = bql, qa1 = 0.f;
    #pragma unroll
    for (int cp = 0; cp < 16; ++cp) {
      uint2 w = WQP2[cp*64 + lane];
      qa0 = fdot2(w.x, bcastu(qpk, 2*cp     ), qa0);
      qa1 = fdot2(w.y, bcastu(qpk, 2*cp + 32), qa1);
    }
    const float qacc = (qa0 + qa1) * 0.25f;
    const u32 qpk2 = pkh(qacc, __shfl_down(qacc, 1));

    // ---- qk[h][c] = Wk_h^T q_h (lane = c), 4 chains, b64 weights ----
    float qkh0=0.f, qkh1=0.f, qkh2=0.f, qkh3=0.f;
    #pragma unroll
    for (int p = 0; p < 8; ++p) {
      uint2 wA = WKP2[ p    *64 + lane];   // {p, p+8}
      uint2 wB = WKP2[(p+8) *64 + lane];   // {p+16, p+24}
      qkh0 = fdot2(wA.x, bcastu(qpk2, 2*p     ), qkh0);
      qkh1 = fdot2(wA.y, bcastu(qpk2, 2*p + 16), qkh1);
      qkh2 = fdot2(wB.x, bcastu(qpk2, 2*p + 32), qkh2);
      qkh3 = fdot2(wB.y, bcastu(qpk2, 2*p + 48), qkh3);
    }
    // pack qk: even lane j packs ch-pair j for all 4 heads -> QKH2[hp][j]
    {
      float t0 = __shfl_down(qkh0, 1), t1 = __shfl_down(qkh1, 1);
      float t2 = __shfl_down(qkh2, 1), t3 = __shfl_down(qkh3, 1);
      if ((lane & 1) == 0) {
        int j = lane >> 1;
        uint2 v0; v0.x = pkh(qkh0, t0); v0.y = pkh(qkh1, t1);
        uint2 v1; v1.x = pkh(qkh2, t2); v1.y = pkh(qkh3, t3);
        QKH2[j]      = v0;
        QKH2[32 + j] = v1;
      }
    }

    // ---- scores: lane -> key cl, heads (2hp, 2hp+1); b64 KF + b64 QK ----
    float s00=0.f, s01=0.f, s10=0.f, s11=0.f;
    {
      const u32* kfrow = KFp + cl*34;
      const uint2* qrow = QKH2 + hp*32;
      #pragma unroll
      for (int c2 = 0; c2 < 16; ++c2) {
        uint2 kf = *(const uint2*)(kfrow + 2*c2);
        uint2 q0 = qrow[2*c2];
        uint2 q1 = qrow[2*c2 + 1];
        s00 = fdot2(kf.x, q0.x, s00);
        s10 = fdot2(kf.x, q0.y, s10);
        s01 = fdot2(kf.y, q1.x, s01);
        s11 = fdot2(kf.y, q1.y, s11);
      }
    }
    float sc0 = s00 + s01, sc1 = s10 + s11;
    if (mk) { sc0 = -1e30f; sc1 = -1e30f; }

    // ---- softmax over k within each 32-lane half ----
    float m0 = sc0, m1 = sc1;
    #pragma unroll
    for (int off = 16; off; off >>= 1) {
      m0 = fmaxf(m0, __shfl_xor(m0, off));
      m1 = fmaxf(m1, __shfl_xor(m1, off));
    }
    float p0 = __expf(sc0 - m0), p1 = __expf(sc1 - m1);
    float s0 = p0, s1 = p1;
    #pragma unroll
    for (int off = 16; off; off >>= 1) {
      s0 += __shfl_xor(s0, off);
      s1 += __shfl_xor(s1, off);
    }
    const float a0 = p0 / s0, a1 = p1 / s1;

    // splatted attn pairs -> API2 (aliases QKH2; scores reads are done)
    {
      uint2 ap; ap.x = pkh(a0, a0); ap.y = pkh(a1, a1);
      API2[lane] = ap;
    }

    // ---- PV: lane -> ch-pair j, heads (2hp,2hp+1); b32 KF col + b64 attn ----
    const int j = lane & 31;
    const int ab = hp << 5;
    hv2 accA = z2, accB = z2;
    #pragma unroll
    for (int k2 = 0; k2 < 32; ++k2) {
      hv2 kf = as_hv(KFp[k2*34 + j]);
      uint2 ap = API2[ab + k2];
      accA = hfma2v(kf, as_hv(ap.x), accA);
      accB = hfma2v(kf, as_hv(ap.y), accB);
    }
    {
      const int sj = (j & 15)*2 + (j >> 4);
      SPP[(2*hp  )*34 + sj] = as_u32h(accA);
      SPP[(2*hp+1)*34 + sj] = as_u32h(accB);
    }

    // ---- ctx[i] = Wv_h S[h] + bv (lane = i, h = i>>4); b64 S + b64 W ----
    float ca0 = bvl, ca1 = 0.f;
    {
      const u32* sprow = SPP + hh*34;
      #pragma unroll
      for (int cp = 0; cp < 16; ++cp) {
        uint2 s = *(const uint2*)(sprow + 2*cp);
        uint2 w = WVP2[cp*64 + lane];
        ca0 = fdot2(w.x, s.x, ca0);
        ca1 = fdot2(w.y, s.y, ca1);
      }
    }
    const float cacc = ca0 + ca1;
    const u32 cpk = pkh(cacc, __shfl_down(cacc, 1));

    // ---- attend = Wo ctx + bo (lane = j), b64 weights ----
    float oa0 = bol, oa1 = 0.f;
    #pragma unroll
    for (int cp = 0; cp < 16; ++cp) {
      uint2 w = WOP2[cp*64 + lane];
      oa0 = fdot2(w.x, bcastu(cpk, 2*cp     ), oa0);
      oa1 = fdot2(w.y, bcastu(cpk, 2*cp + 32), oa1);
    }
    const float aacc = oa0 + oa1;

    float x1 = vfl + aacc;
    x1pre[(u32)n*64u + (u32)lane] = x1;
    ssum += x1; ssq = fmaf(x1, x1, ssq);
  }

  // ---- block-reduce BN1 partials ----
  __syncthreads();
  float* red = (float*)smem;
  red[wid*64 + lane] = ssum;
  red[512 + wid*64 + lane] = ssq;
  __syncthreads();
  if (wid == 0) {
    float t1 = 0.f, t2 = 0.f;
    #pragma unroll
    for (int w = 0; w < 8; ++w) { t1 += red[w*64+lane]; t2 += red[512+w*64+lane]; }
    atomicAdd(&stats[lane], t1);
    atomicAdd(&stats[64+lane], t2);
  }
}

// ---------------------------------------------------------------------------
// K3 (MFMA): x2pre = x1 + FFN(BN1(x1pre)); BN2 partials.  (frozen, round 11)
// ---------------------------------------------------------------------------
__global__ __launch_bounds__(512) void k3_mfma(
    const float* __restrict__ x1pre, float* __restrict__ stats,
    const float* __restrict__ g1, const float* __restrict__ b1,
    const float* __restrict__ l1w, const float* __restrict__ l1b,
    const float* __restrict__ l2w, const float* __restrict__ l2b,
    float* __restrict__ x2pre)
{
  extern __shared__ char smem[];
  u32*   W1B  = (u32*)smem;
  u32*   W2B  = W1B + 8192;
  u16*   XA   = (u16*)(W2B + 8192);
  u16*   H    = XA + 4608;
  float* l1bs = (float*)(H + 16896);
  float* l2bs = l1bs + 256;
  float* scb  = l2bs + 64;
  float* shb  = scb + 64;
  float* red  = shb + 64;
  const int tid = threadIdx.x, wid = tid >> 6, lane = tid & 63;

  for (int e = tid; e < 8192; e += 512) {
    int j2 = e & 3, col = (e>>2) & 15, g = (e>>6) & 3, kk = (e>>8) & 1, n = e >> 9;
    int f = 16*n + col, k = kk*32 + g*8 + 2*j2;
    W1B[e] = pkh(l1w[f*64 + k], l1w[f*64 + k + 1]);
  }
  for (int e = tid; e < 8192; e += 512) {
    int j2 = e & 3, col = (e>>2) & 15, g = (e>>6) & 3, kk = (e>>8) & 7, n = e >> 11;
    int c = 16*n + col, k = kk*32 + g*8 + 2*j2;
    W2B[e] = pkh(l2w[c*256 + k], l2w[c*256 + k + 1]);
  }
  if (tid < 256) l1bs[tid] = l1b[tid];
  if (tid < 64)  l2bs[tid] = l2b[tid];
  if (tid < 64) {
    float mean = stats[tid] * (1.f/NV);
    float var  = stats[64+tid] * (1.f/NV) - mean*mean;
    float sc = rsqrtf(var + EPSB) * g1[tid];
    scb[tid] = sc;
    shb[tid] = b1[tid] - mean * sc;
  }
  if (tid < 128) red[tid] = 0.f;

  const int m  = wid & 3;
  const int wh = wid >> 2;
  const int lg = lane >> 4, ll = lane & 15;
  float ss0 = 0.f, sq0 = 0.f, ss1 = 0.f, sq1 = 0.f;

  for (int tile = blockIdx.x; tile < 1563; tile += 256) {
    const int base = tile * 64;
    __syncthreads();
    {
      int row = tid >> 3, cq = (tid & 7) * 8;
      int srow = base + row; if (srow >= NV) srow = NV - 1;
      const float* src = x1pre + (size_t)srow*64 + cq;
      u32* dst = (u32*)XA + row*36 + (tid & 7)*4;
      #pragma unroll
      for (int q = 0; q < 4; ++q) {
        float v0 = src[2*q]   * scb[cq+2*q]   + shb[cq+2*q];
        float v1 = src[2*q+1] * scb[cq+2*q+1] + shb[cq+2*q+1];
        dst[q] = pkh(v0, v1);
      }
    }
    __syncthreads();
    {
      const u16* arow = XA + (16*m + ll)*72 + lg*8;
      h8 a0 = *(const h8*)(arow);
      h8 a1 = *(const h8*)(arow + 32);
      #pragma unroll
      for (int nn = 0; nn < 8; ++nn) {
        int n = 8*wh + nn;
        const u32* bb = W1B + (n*8 + lg)*64 + ll*4;
        h8 b0 = *(const h8*)(bb);
        h8 b1v = *(const h8*)(bb + 256);
        f32x4 acc = {0.f, 0.f, 0.f, 0.f};
        acc = mfma16(a0, b0, acc);
        acc = mfma16(a1, b1v, acc);
        float bias = l1bs[16*n + ll];
        u16* hw = H + (16*m + lg*4)*264 + 16*n + ll;
        #pragma unroll
        for (int r = 0; r < 4; ++r)
          hw[r*264] = f2h(fmaxf(acc[r] + bias, 0.f));
      }
    }
    __syncthreads();
    {
      const u16* arow = H + (16*m + ll)*264 + lg*8;
      h8 a[8];
      #pragma unroll
      for (int kk = 0; kk < 8; ++kk) a[kk] = *(const h8*)(arow + kk*32);
      #pragma unroll
      for (int nn = 0; nn < 2; ++nn) {
        int n = 2*wh + nn;
        const u32* bb = W2B + (n*32 + lg)*64 + ll*4;
        f32x4 acA = {0.f,0.f,0.f,0.f}, acB = {0.f,0.f,0.f,0.f};
        #pragma unroll
        for (int kk = 0; kk < 8; kk += 2) {
          h8 b0 = *(const h8*)(bb + kk*256);
          h8 b1v = *(const h8*)(bb + (kk+1)*256);
          acA = mfma16(a[kk],   b0,  acA);
          acB = mfma16(a[kk+1], b1v, acB);
        }
        const int col = 16*n + ll;
        const float bias = l2bs[col];
        const u16* xr = XA + (16*m + lg*4)*72 + col;
        const int vox0 = base + 16*m + lg*4;
        float ss = 0.f, sq = 0.f;
        #pragma unroll
        for (int r = 0; r < 4; ++r) {
          int vox = vox0 + r;
          if (vox < NV) {
            float y = acA[r] + acB[r] + bias + h2f(xr[r*72]);
            x2pre[(size_t)vox*64 + col] = y;
            ss += y; sq = fmaf(y, y, sq);
          }
        }
        if (nn == 0) { ss0 += ss; sq0 += sq; } else { ss1 += ss; sq1 += sq; }
      }
    }
  }

  __syncthreads();
  const int c2a = 16*(2*wh)     + ll;
  const int c2b = 16*(2*wh + 1) + ll;
  atomicAdd(&red[c2a], ss0);
  atomicAdd(&red[64 + c2a], sq0);
  atomicAdd(&red[c2b], ss1);
  atomicAdd(&red[64 + c2b], sq1);
  __syncthreads();
  if (tid < 64) {
    atomicAdd(&stats[128+tid], red[tid]);
    atomicAdd(&stats[192+tid], red[64+tid]);
  }
}

// ---------------------------------------------------------------------------
// K4: x2 = BN2(x2pre); outpre = x2 @ out_w^T + out_b; BN3 partials. (frozen)
// ---------------------------------------------------------------------------
__global__ __launch_bounds__(256) void k4_out(
    const float* __restrict__ x2pre, float* __restrict__ stats,
    const float* __restrict__ g2, const float* __restrict__ b2,
    const float* __restrict__ outw, const float* __restrict__ outb,
    float* __restrict__ outpre)
{
  extern __shared__ char smem[];
  u32* WTP = (u32*)smem;
  const int tid = threadIdx.x, wid = tid >> 6, lane = tid & 63;
  for (int t = tid; t < 2048; t += 256) {
    int cp = t >> 6, o = t & 63;
    WTP[t] = pkh(outw[o*64 + 2*cp], outw[o*64 + 2*cp + 1]);
  }
  __syncthreads();

  const float mean = stats[128+lane] * (1.f/NV);
  const float var  = stats[192+lane] * (1.f/NV) - mean*mean;
  const float sc   = rsqrtf(var + EPSB) * g2[lane];
  const float sh   = b2[lane] - mean * sc;
  const float obl  = outb[lane];
  float ssum = 0.f, ssq = 0.f;

  const int stride = gridDim.x << 4;
  for (int n0 = blockIdx.x*16 + wid*4; n0 < NV; n0 += stride) {
    float xa = x2pre[(size_t) n0   *64+lane] * sc + sh;
    float xb = x2pre[(size_t)(n0+1)*64+lane] * sc + sh;
    float xc = x2pre[(size_t)(n0+2)*64+lane] * sc + sh;
    float xd = x2pre[(size_t)(n0+3)*64+lane] * sc + sh;
    const u32 xpa = pkh(xa, __shfl_down(xa,1));
    const u32 xpb = pkh(xb, __shfl_down(xb,1));
    const u32 xpc = pkh(xc, __shfl_down(xc,1));
    const u32 xpd = pkh(xd, __shfl_down(xd,1));
    float a0 = obl, a1 = obl, a2 = obl, a3 = obl;
    #pragma unroll 8
    for (int cp = 0; cp < 32; ++cp) {
      u32 w = WTP[cp*64 + lane];
      a0 = fdot2(w, bcastu(xpa, 2*cp), a0);
      a1 = fdot2(w, bcastu(xpb, 2*cp), a1);
      a2 = fdot2(w, bcastu(xpc, 2*cp), a2);
      a3 = fdot2(w, bcastu(xpd, 2*cp), a3);
    }
    outpre[(size_t) n0   *64+lane] = a0;
    outpre[(size_t)(n0+1)*64+lane] = a1;
    outpre[(size_t)(n0+2)*64+lane] = a2;
    outpre[(size_t)(n0+3)*64+lane] = a3;
    ssum += (a0 + a1) + (a2 + a3);
    ssq = fmaf(a0,a0, fmaf(a1,a1, fmaf(a2,a2, fmaf(a3,a3, ssq))));
  }

  __syncthreads();
  float* red = (float*)smem;
  red[wid*64+lane] = ssum;
  red[256 + wid*64 + lane] = ssq;
  __syncthreads();
  if (wid == 0) {
    float t1 = 0.f, t2 = 0.f;
    #pragma unroll
    for (int w = 0; w < 4; ++w) { t1 += red[w*64+lane]; t2 += red[256+w*64+lane]; }
    atomicAdd(&stats[256+lane], t1);
    atomicAdd(&stats[320+lane], t2);
  }
}

// ---------------------------------------------------------------------------
// K5: out = relu(BN3(outpre))  (frozen)
// ---------------------------------------------------------------------------
__global__ __launch_bounds__(256) void k5_fin(
    const float* __restrict__ outpre, const float* __restrict__ stats,
    const float* __restrict__ g3, const float* __restrict__ b3,
    float* __restrict__ out)
{
  const int t = blockIdx.x*256 + threadIdx.x;
  const int c0 = (t*4) & 63;
  float sc[4], sh[4];
  #pragma unroll
  for (int j = 0; j < 4; ++j) {
    int c = c0 + j;
    float mean = stats[256+c] * (1.f/NV);
    float var  = stats[320+c] * (1.f/NV) - mean*mean;
    sc[j] = rsqrtf(var + EPSB) * g3[c];
    sh[j] = b3[c] - mean*sc[j];
  }
  for (int i = t; i < NV*16; i += 131072) {
    float4 v = *(const float4*)&outpre[(size_t)i*4];
    v.x = fmaxf(fmaf(v.x, sc[0], sh[0]), 0.f);
    v.y = fmaxf(fmaf(v.y, sc[1], sh[1]), 0.f);
    v.z = fmaxf(fmaf(v.z, sc[2], sh[2]), 0.f);
    v.w = fmaxf(fmaf(v.w, sc[3], sh[3]), 0.f);
    *(float4*)&out[(size_t)i*4] = v;
  }
}

extern "C" void kernel_launch(void* const* d_in, const int* in_sizes, int n_in,
                              void* d_out, int out_size, void* d_ws, size_t ws_size,
                              hipStream_t stream) {
  (void)in_sizes; (void)n_in; (void)out_size; (void)ws_size;
  const float* vf     = (const float*)d_in[0];
  const float* coords = (const float*)d_in[1];
  const int*   kidx   = (const int*)d_in[2];
  const void*  kmask  = d_in[3];
  const float* wq  = (const float*)d_in[4];  const float* bq  = (const float*)d_in[5];
  const float* wk  = (const float*)d_in[6];  /* bk cancels in softmax */
  const float* wv  = (const float*)d_in[8];  const float* bv  = (const float*)d_in[9];
  const float* wo  = (const float*)d_in[10]; const float* bo  = (const float*)d_in[11];
  const float* qpw = (const float*)d_in[12]; const float* qpb = (const float*)d_in[13];
  const float* kpw = (const float*)d_in[14]; const float* kpb = (const float*)d_in[15];
  const float* g1  = (const float*)d_in[16]; const float* b1  = (const float*)d_in[17];
  const float* g2  = (const float*)d_in[18]; const float* b2  = (const float*)d_in[19];
  const float* l1w = (const float*)d_in[20]; const float* l1b = (const float*)d_in[21];
  const float* l2w = (const float*)d_in[22]; const float* l2b = (const float*)d_in[23];
  const float* outw= (const float*)d_in[24]; const float* outb= (const float*)d_in[25];
  const float* g3  = (const float*)d_in[26]; const float* b3  = (const float*)d_in[27];

  float* wsf    = (float*)d_ws;
  float* x1pre  = wsf;                       // [N*64]
  float* x2pre  = wsf + (size_t)NV*64;       // [N*64]; aliases VP before K3
  u32*   VP     = (u32*)x2pre;               // packed (vf,P) f16 table, dead after K1
  float* outpre = x1pre;                     // alias: x1pre dead after K3
  float* stats  = wsf + (size_t)2*NV*64;     // [384]
  int*   mflag  = (int*)(stats + 384);

  (void)hipMemsetAsync(stats, 0, 384*sizeof(float), stream);

  (void)hipFuncSetAttribute((const void*)k1_attn, hipFuncAttributeMaxDynamicSharedMemorySize, 76288);
  (void)hipFuncSetAttribute((const void*)k3_mfma, hipFuncAttributeMaxDynamicSharedMemorySize, 110848);

  k0_detect<<<1, 256, 0, stream>>>((const u32*)kmask, mflag);
  k_prep<<<2048, 256, 0, stream>>>(vf, coords, kpw, VP);
  k1_attn<<<512, 512, 76288, stream>>>(vf, coords, kidx, kmask, mflag, VP,
      wq, bq, wk, wv, bv, wo, bo, qpw, qpb, kpb, x1pre, stats);
  k3_mfma<<<256, 512, 110848, stream>>>(x1pre, stats, g1, b1, l1w, l1b, l2w, l2b, x2pre);
  k4_out<<<1024, 256, 8192, stream>>>(x2pre, stats, g2, b2, outw, outb, outpre);
  k5_fin<<<512, 256, 0, stream>>>(outpre, stats, g3, b3, (float*)d_out);
}

// Round 13
// 299.698 us; speedup vs baseline: 1.5011x; 1.0146x over previous
//
#include <hip/hip_runtime.h>
#include <hip/hip_bf16.h>

#define NV 100000
#define EPSB 1e-5f

typedef unsigned short u16;
typedef unsigned int u32;
typedef _Float16 hv2 __attribute__((ext_vector_type(2)));
typedef _Float16 h8  __attribute__((ext_vector_type(8)));
typedef float f32x4  __attribute__((ext_vector_type(4)));

__device__ __forceinline__ u32 pkh(float x, float y) {
  auto h = __builtin_amdgcn_cvt_pkrtz(x, y);
  union { decltype(h) v; u32 u; } c; c.v = h; return c.u;
}
__device__ __forceinline__ float fdot2(u32 w, u32 x, float acc) {
#if __has_builtin(__builtin_amdgcn_fdot2)
  union { u32 u; hv2 h; } a, b; a.u = w; b.u = x;
  return __builtin_amdgcn_fdot2(a.h, b.h, acc, false);
#else
  union { u32 u; hv2 h; } a, b; a.u = w; b.u = x;
  return acc + (float)a.h.x*(float)b.h.x + (float)a.h.y*(float)b.h.y;
#endif
}
__device__ __forceinline__ u32 bcastu(u32 v, int l) {
  return (u32)__builtin_amdgcn_readlane((int)v, l);
}
__device__ __forceinline__ hv2 as_hv(u32 u) {
  union { u32 u; hv2 h; } c; c.u = u; return c.h;
}
__device__ __forceinline__ u32 as_u32h(hv2 h) {
  union { hv2 h; u32 u; } c; c.h = h; return c.u;
}
__device__ __forceinline__ hv2 hmax2v(hv2 a, hv2 b) {
#if __has_builtin(__builtin_elementwise_max)
  return __builtin_elementwise_max(a, b);
#else
  hv2 r; r.x = a.x > b.x ? a.x : b.x; r.y = a.y > b.y ? a.y : b.y; return r;
#endif
}
__device__ __forceinline__ hv2 hfma2v(hv2 a, hv2 b, hv2 c) {
#if __has_builtin(__builtin_elementwise_fma)
  return __builtin_elementwise_fma(a, b, c);
#else
  return a * b + c;
#endif
}
__device__ __forceinline__ u16 f2h(float x) { return (u16)(pkh(x, x) & 0xffffu); }
__device__ __forceinline__ float h2f(u16 u) {
  union { u16 u; _Float16 h; } c; c.u = u; return (float)c.h;
}
__device__ __forceinline__ f32x4 mfma16(h8 a, h8 b, f32x4 c) {
  return __builtin_amdgcn_mfma_f32_16x16x32_f16(a, b, c, 0, 0, 0);
}

// ---------------------------------------------------------------------------
// K0: detect key_mask element width (int32 vs byte-bool).
// ---------------------------------------------------------------------------
__global__ void k0_detect(const u32* __restrict__ km, int* __restrict__ flag) {
  int bad = 0;
  for (int i = threadIdx.x; i < 4096; i += 256) {
    u32 v = km[i];
    bad |= (v != 0u && v != 1u && v != 0x3F800000u) ? 1 : 0;
  }
  unsigned long long m = __ballot(bad != 0);
  __shared__ int sbad[4];
  if ((threadIdx.x & 63) == 0) sbad[threadIdx.x >> 6] = (m != 0ull);
  __syncthreads();
  if (threadIdx.x == 0) flag[0] = !(sbad[0] | sbad[1] | sbad[2] | sbad[3]);
}

// ---------------------------------------------------------------------------
// Kprep: VP[m][cp] = { pkh(vf pair), pkh(P pair) }  (frozen, round 8)
// ---------------------------------------------------------------------------
__global__ __launch_bounds__(256) void k_prep(
    const float* __restrict__ vf, const float* __restrict__ coords,
    const float* __restrict__ kpw, u32* __restrict__ VP)
{
  const int t = blockIdx.x*256 + threadIdx.x;
  const int cp = t & 31;
  const float wa0 = kpw[(2*cp)*3],   wa1 = kpw[(2*cp)*3+1],   wa2 = kpw[(2*cp)*3+2];
  const float wb0 = kpw[(2*cp+1)*3], wb1 = kpw[(2*cp+1)*3+1], wb2 = kpw[(2*cp+1)*3+2];
  for (int e = t; e < NV*32; e += 524288) {
    const int m = e >> 5;
    const float2 v2 = *(const float2*)&vf[(u32)m*64u + 2u*(u32)cp];
    const float c0 = coords[m*3], c1 = coords[m*3+1], c2 = coords[m*3+2];
    const float P0 = fmaf(wa0, c0, fmaf(wa1, c1, wa2*c2));
    const float P1 = fmaf(wb0, c0, fmaf(wb1, c1, wb2*c2));
    uint2 o; o.x = pkh(v2.x, v2.y); o.y = pkh(P0, P1);
    *(uint2*)&VP[(u32)e*2u] = o;
  }
}

// ---------------------------------------------------------------------------
// K1: gather attention.  Round-13: software-pipelined voxel loop —
// (1) issue all 16 gathers FIRST, (2) prefetch next voxel's kidx/scalars,
// (3) gather-independent q/qk dot2 stretch hides the latency, (4) pack,
// (5) scores/softmax/PV/ctx/wo.  Math bit-identical to round 12.
// ---------------------------------------------------------------------------
__global__ __launch_bounds__(512, 4) void k1_attn(
    const float* __restrict__ vf, const float* __restrict__ coords,
    const int* __restrict__ kidx, const void* __restrict__ kmaskv,
    const int* __restrict__ mflag, const u32* __restrict__ VP,
    const float* __restrict__ wq, const float* __restrict__ bq,
    const float* __restrict__ wk,
    const float* __restrict__ wv, const float* __restrict__ bv,
    const float* __restrict__ wo, const float* __restrict__ bo,
    const float* __restrict__ qpw, const float* __restrict__ qpb,
    const float* __restrict__ kpb,
    float* __restrict__ x1pre, float* __restrict__ stats)
{
  extern __shared__ char smem[];
  uint2* WQP2 = (uint2*)smem;        // [cp 0..15][i]: {wq cp, wq cp+16} 8KB
  uint2* WKP2 = WQP2 + 1024;         // [p 0..15][c]: p<8 {p,p+8} else {p+8,p+16}
  uint2* WVP2 = WKP2 + 1024;
  uint2* WOP2 = WVP2 + 1024;
  const int tid = threadIdx.x, wid = tid >> 6, lane = tid & 63;

  for (int t = tid; t < 1024; t += 512) {
    int cp = t >> 6, i = t & 63;
    uint2 v;
    v.x = pkh(wq[i*64 + 2*cp],      wq[i*64 + 2*cp + 1]);
    v.y = pkh(wq[i*64 + 2*cp + 32], wq[i*64 + 2*cp + 33]);
    WQP2[t] = v;
    int lo = (cp < 8) ? cp : cp + 8, hi = lo + 8;
    v.x = pkh(wk[2*lo*64 + i], wk[(2*lo+1)*64 + i]);
    v.y = pkh(wk[2*hi*64 + i], wk[(2*hi+1)*64 + i]);
    WKP2[t] = v;
    v.x = pkh(wv[i*64 + 2*cp],      wv[i*64 + 2*cp + 1]);
    v.y = pkh(wv[i*64 + 2*cp + 32], wv[i*64 + 2*cp + 33]);
    WVP2[t] = v;
    v.x = pkh(wo[i*64 + 2*cp],      wo[i*64 + 2*cp + 1]);
    v.y = pkh(wo[i*64 + 2*cp + 32], wo[i*64 + 2*cp + 33]);
    WOP2[t] = v;
  }
  __syncthreads();

  u32* wbase = (u32*)(smem + 32768) + wid * 1360;
  u32*   KFp  = wbase;                    // [32 keys][34] f16 c-pairs (pitch 34)
  uint2* QKH2 = (uint2*)(wbase + 1088);   // [hp][cp 0..31]: {head 2hp, 2hp+1}
  uint2* API2 = QKH2;                     // alias: attn pairs after scores
  u32*   SPP  = wbase + 1216;             // [4 heads][34]: interleave {cp, cp+16}

  const int cl = lane & 31, kh = lane >> 5, hp = lane >> 5, hh = lane >> 4;
  const int ca = 2*cl;
  const float qp0 = qpw[lane*3], qp1 = qpw[lane*3+1], qp2 = qpw[lane*3+2], qpbl = qpb[lane];
  const hv2 kpbp = as_hv(pkh(kpb[ca], kpb[ca+1]));
  const hv2 z2 = (hv2)(_Float16)0;
  const float bql = bq[lane], bvl = bv[lane], bol = bo[lane];
  const int mode4 = mflag[0];
  const u32* km32 = (const u32*)kmaskv;
  const unsigned char* km8 = (const unsigned char*)kmaskv;
  float ssum = 0.f, ssq = 0.f;

  union iu_t { int4 v[4]; int s[16]; };

  const int n0 = blockIdx.x*8 + wid;
  // ---- prologue: load voxel n0's indices + scalars ----
  iu_t iu;
  float cn0 = 0.f, cn1 = 0.f, cn2 = 0.f, vfl = 0.f;
  uint2 wn = {0u, 0u};
  u32 mkraw = 0u;
  if (n0 < NV) {
    const int4* kp4 = (const int4*)(kidx + (u32)n0*32u + (u32)(kh*16));
    iu.v[0] = kp4[0]; iu.v[1] = kp4[1]; iu.v[2] = kp4[2]; iu.v[3] = kp4[3];
    cn0 = coords[n0*3]; cn1 = coords[n0*3+1]; cn2 = coords[n0*3+2];
    vfl = vf[(u32)n0*64u + (u32)lane];
    wn  = *(const uint2*)&VP[(u32)n0*64u + (u32)ca];
    mkraw = mode4 ? km32[n0*32 + cl] : (u32)km8[n0*32 + cl];
  }

  for (int n = n0; n < NV; n += 4096) {
    // ---- 1. issue all 16 gathers for n (latency hidden by step 2+3) ----
    uint2 g[16];
    #pragma unroll
    for (int k = 0; k < 16; ++k) {
      const u32 off = ((u32)iu.s[k] << 6) + (u32)ca;
      g[k] = *(const uint2*)&VP[off];
    }

    // ---- 2. prefetch next voxel's indices + scalars ----
    const int nn = n + 4096;
    const int np = (nn < NV) ? nn : n;     // clamped dummy on tail
    iu_t iun;
    {
      const int4* kp4 = (const int4*)(kidx + (u32)np*32u + (u32)(kh*16));
      iun.v[0] = kp4[0]; iun.v[1] = kp4[1]; iun.v[2] = kp4[2]; iun.v[3] = kp4[3];
    }
    const float cn0n = coords[np*3], cn1n = coords[np*3+1], cn2n = coords[np*3+2];
    const float vfln = vf[(u32)np*64u + (u32)lane];
    const uint2 wnn  = *(const uint2*)&VP[(u32)np*64u + (u32)ca];
    const u32 mkrawn = mode4 ? km32[np*32 + cl] : (u32)km8[np*32 + cl];

    const hv2 pnp = as_hv(wn.y) - kpbp;
    const u32 mk = (mkraw != 0u);

    // ---- 3. gather-independent compute: query, q, qk ----
    float query = vfl + fmaxf(fmaf(qp0,cn0,fmaf(qp1,cn1,fmaf(qp2,cn2,qpbl))), 0.f);
    const u32 qpk = pkh(query, __shfl_down(query, 1));

    float qa0 = bql, qa1 = 0.f;
    #pragma unroll
    for (int cp = 0; cp < 16; ++cp) {
      uint2 w = WQP2[cp*64 + lane];
      qa0 = fdot2(w.x, bcastu(qpk, 2*cp     ), qa0);
      qa1 = fdot2(w.y, bcastu(qpk, 2*cp + 32), qa1);
    }
    const float qacc = (qa0 + qa1) * 0.25f;
    const u32 qpk2 = pkh(qacc, __shfl_down(qacc, 1));

    float qkh0=0.f, qkh1=0.f, qkh2=0.f, qkh3=0.f;
    #pragma unroll
    for (int p = 0; p < 8; ++p) {
      uint2 wA = WKP2[ p    *64 + lane];
      uint2 wB = WKP2[(p+8) *64 + lane];
      qkh0 = fdot2(wA.x, bcastu(qpk2, 2*p     ), qkh0);
      qkh1 = fdot2(wA.y, bcastu(qpk2, 2*p + 16), qkh1);
      qkh2 = fdot2(wB.x, bcastu(qpk2, 2*p + 32), qkh2);
      qkh3 = fdot2(wB.y, bcastu(qpk2, 2*p + 48), qkh3);
    }
    {
      float t0 = __shfl_down(qkh0, 1), t1 = __shfl_down(qkh1, 1);
      float t2 = __shfl_down(qkh2, 1), t3 = __shfl_down(qkh3, 1);
      if ((lane & 1) == 0) {
        int j = lane >> 1;
        uint2 v0; v0.x = pkh(qkh0, t0); v0.y = pkh(qkh1, t1);
        uint2 v1; v1.x = pkh(qkh2, t2); v1.y = pkh(qkh3, t3);
        QKH2[j]      = v0;
        QKH2[32 + j] = v1;
      }
    }

    // ---- 4. pack gathered keys -> KFp (gathers have returned by now) ----
    #pragma unroll
    for (int k = 0; k < 16; ++k) {
      hv2 pe = hmax2v(as_hv(g[k].y) - pnp, z2);
      KFp[(kh*16 + k)*34 + cl] = as_u32h(as_hv(g[k].x) + pe);
    }

    // ---- 5. scores: lane -> key cl, heads (2hp, 2hp+1) ----
    float s00=0.f, s01=0.f, s10=0.f, s11=0.f;
    {
      const u32* kfrow = KFp + cl*34;
      const uint2* qrow = QKH2 + hp*32;
      #pragma unroll
      for (int c2 = 0; c2 < 16; ++c2) {
        uint2 kf = *(const uint2*)(kfrow + 2*c2);
        uint2 q0 = qrow[2*c2];
        uint2 q1 = qrow[2*c2 + 1];
        s00 = fdot2(kf.x, q0.x, s00);
        s10 = fdot2(kf.x, q0.y, s10);
        s01 = fdot2(kf.y, q1.x, s01);
        s11 = fdot2(kf.y, q1.y, s11);
      }
    }
    float sc0 = s00 + s01, sc1 = s10 + s11;
    if (mk) { sc0 = -1e30f; sc1 = -1e30f; }

    // ---- softmax over k within each 32-lane half ----
    float m0 = sc0, m1 = sc1;
    #pragma unroll
    for (int off = 16; off; off >>= 1) {
      m0 = fmaxf(m0, __shfl_xor(m0, off));
      m1 = fmaxf(m1, __shfl_xor(m1, off));
    }
    float p0 = __expf(sc0 - m0), p1 = __expf(sc1 - m1);
    float s0 = p0, s1 = p1;
    #pragma unroll
    for (int off = 16; off; off >>= 1) {
      s0 += __shfl_xor(s0, off);
      s1 += __shfl_xor(s1, off);
    }
    const float a0 = p0 / s0, a1 = p1 / s1;

    {
      uint2 ap; ap.x = pkh(a0, a0); ap.y = pkh(a1, a1);
      API2[lane] = ap;
    }

    // ---- PV: lane -> ch-pair j, heads (2hp,2hp+1) ----
    const int j = lane & 31;
    const int ab = hp << 5;
    hv2 accA = z2, accB = z2;
    #pragma unroll
    for (int k2 = 0; k2 < 32; ++k2) {
      hv2 kf = as_hv(KFp[k2*34 + j]);
      uint2 ap = API2[ab + k2];
      accA = hfma2v(kf, as_hv(ap.x), accA);
      accB = hfma2v(kf, as_hv(ap.y), accB);
    }
    {
      const int sj = (j & 15)*2 + (j >> 4);
      SPP[(2*hp  )*34 + sj] = as_u32h(accA);
      SPP[(2*hp+1)*34 + sj] = as_u32h(accB);
    }

    // ---- ctx[i] = Wv_h S[h] + bv (lane = i, h = i>>4) ----
    float ca0 = bvl, ca1 = 0.f;
    {
      const u32* sprow = SPP + hh*34;
      #pragma unroll
      for (int cp = 0; cp < 16; ++cp) {
        uint2 s = *(const uint2*)(sprow + 2*cp);
        uint2 w = WVP2[cp*64 + lane];
        ca0 = fdot2(w.x, s.x, ca0);
        ca1 = fdot2(w.y, s.y, ca1);
      }
    }
    const float cacc = ca0 + ca1;
    const u32 cpk = pkh(cacc, __shfl_down(cacc, 1));

    // ---- attend = Wo ctx + bo (lane = j) ----
    float oa0 = bol, oa1 = 0.f;
    #pragma unroll
    for (int cp = 0; cp < 16; ++cp) {
      uint2 w = WOP2[cp*64 + lane];
      oa0 = fdot2(w.x, bcastu(cpk, 2*cp     ), oa0);
      oa1 = fdot2(w.y, bcastu(cpk, 2*cp + 32), oa1);
    }
    const float aacc = oa0 + oa1;

    float x1 = vfl + aacc;
    x1pre[(u32)n*64u + (u32)lane] = x1;
    ssum += x1; ssq = fmaf(x1, x1, ssq);

    // ---- 6. rotate prefetched state ----
    iu = iun;
    cn0 = cn0n; cn1 = cn1n; cn2 = cn2n;
    vfl = vfln; wn = wnn; mkraw = mkrawn;
  }

  // ---- block-reduce BN1 partials ----
  __syncthreads();
  float* red = (float*)smem;
  red[wid*64 + lane] = ssum;
  red[512 + wid*64 + lane] = ssq;
  __syncthreads();
  if (wid == 0) {
    float t1 = 0.f, t2 = 0.f;
    #pragma unroll
    for (int w = 0; w < 8; ++w) { t1 += red[w*64+lane]; t2 += red[512+w*64+lane]; }
    atomicAdd(&stats[lane], t1);
    atomicAdd(&stats[64+lane], t2);
  }
}

// ---------------------------------------------------------------------------
// K3 (MFMA): x2pre = x1 + FFN(BN1(x1pre)); BN2 partials.  (frozen, round 11)
// ---------------------------------------------------------------------------
__global__ __launch_bounds__(512) void k3_mfma(
    const float* __restrict__ x1pre, float* __restrict__ stats,
    const float* __restrict__ g1, const float* __restrict__ b1,
    const float* __restrict__ l1w, const float* __restrict__ l1b,
    const float* __restrict__ l2w, const float* __restrict__ l2b,
    float* __restrict__ x2pre)
{
  extern __shared__ char smem[];
  u32*   W1B  = (u32*)smem;
  u32*   W2B  = W1B + 8192;
  u16*   XA   = (u16*)(W2B + 8192);
  u16*   H    = XA + 4608;
  float* l1bs = (float*)(H + 16896);
  float* l2bs = l1bs + 256;
  float* scb  = l2bs + 64;
  float* shb  = scb + 64;
  float* red  = shb + 64;
  const int tid = threadIdx.x, wid = tid >> 6, lane = tid & 63;

  for (int e = tid; e < 8192; e += 512) {
    int j2 = e & 3, col = (e>>2) & 15, g = (e>>6) & 3, kk = (e>>8) & 1, n = e >> 9;
    int f = 16*n + col, k = kk*32 + g*8 + 2*j2;
    W1B[e] = pkh(l1w[f*64 + k], l1w[f*64 + k + 1]);
  }
  for (int e = tid; e < 8192; e += 512) {
    int j2 = e & 3, col = (e>>2) & 15, g = (e>>6) & 3, kk = (e>>8) & 7, n = e >> 11;
    int c = 16*n + col, k = kk*32 + g*8 + 2*j2;
    W2B[e] = pkh(l2w[c*256 + k], l2w[c*256 + k + 1]);
  }
  if (tid < 256) l1bs[tid] = l1b[tid];
  if (tid < 64)  l2bs[tid] = l2b[tid];
  if (tid < 64) {
    float mean = stats[tid] * (1.f/NV);
    float var  = stats[64+tid] * (1.f/NV) - mean*mean;
    float sc = rsqrtf(var + EPSB) * g1[tid];
    scb[tid] = sc;
    shb[tid] = b1[tid] - mean * sc;
  }
  if (tid < 128) red[tid] = 0.f;

  const int m  = wid & 3;
  const int wh = wid >> 2;
  const int lg = lane >> 4, ll = lane & 15;
  float ss0 = 0.f, sq0 = 0.f, ss1 = 0.f, sq1 = 0.f;

  for (int tile = blockIdx.x; tile < 1563; tile += 256) {
    const int base = tile * 64;
    __syncthreads();
    {
      int row = tid >> 3, cq = (tid & 7) * 8;
      int srow = base + row; if (srow >= NV) srow = NV - 1;
      const float* src = x1pre + (size_t)srow*64 + cq;
      u32* dst = (u32*)XA + row*36 + (tid & 7)*4;
      #pragma unroll
      for (int q = 0; q < 4; ++q) {
        float v0 = src[2*q]   * scb[cq+2*q]   + shb[cq+2*q];
        float v1 = src[2*q+1] * scb[cq+2*q+1] + shb[cq+2*q+1];
        dst[q] = pkh(v0, v1);
      }
    }
    __syncthreads();
    {
      const u16* arow = XA + (16*m + ll)*72 + lg*8;
      h8 a0 = *(const h8*)(arow);
      h8 a1 = *(const h8*)(arow + 32);
      #pragma unroll
      for (int nn = 0; nn < 8; ++nn) {
        int n = 8*wh + nn;
        const u32* bb = W1B + (n*8 + lg)*64 + ll*4;
        h8 b0 = *(const h8*)(bb);
        h8 b1v = *(const h8*)(bb + 256);
        f32x4 acc = {0.f, 0.f, 0.f, 0.f};
        acc = mfma16(a0, b0, acc);
        acc = mfma16(a1, b1v, acc);
        float bias = l1bs[16*n + ll];
        u16* hw = H + (16*m + lg*4)*264 + 16*n + ll;
        #pragma unroll
        for (int r = 0; r < 4; ++r)
          hw[r*264] = f2h(fmaxf(acc[r] + bias, 0.f));
      }
    }
    __syncthreads();
    {
      const u16* arow = H + (16*m + ll)*264 + lg*8;
      h8 a[8];
      #pragma unroll
      for (int kk = 0; kk < 8; ++kk) a[kk] = *(const h8*)(arow + kk*32);
      #pragma unroll
      for (int nn = 0; nn < 2; ++nn) {
        int n = 2*wh + nn;
        const u32* bb = W2B + (n*32 + lg)*64 + ll*4;
        f32x4 acA = {0.f,0.f,0.f,0.f}, acB = {0.f,0.f,0.f,0.f};
        #pragma unroll
        for (int kk = 0; kk < 8; kk += 2) {
          h8 b0 = *(const h8*)(bb + kk*256);
          h8 b1v = *(const h8*)(bb + (kk+1)*256);
          acA = mfma16(a[kk],   b0,  acA);
          acB = mfma16(a[kk+1], b1v, acB);
        }
        const int col = 16*n + ll;
        const float bias = l2bs[col];
        const u16* xr = XA + (16*m + lg*4)*72 + col;
        const int vox0 = base + 16*m + lg*4;
        float ss = 0.f, sq = 0.f;
        #pragma unroll
        for (int r = 0; r < 4; ++r) {
          int vox = vox0 + r;
          if (vox < NV) {
            float y = acA[r] + acB[r] + bias + h2f(xr[r*72]);
            x2pre[(size_t)vox*64 + col] = y;
            ss += y; sq = fmaf(y, y, sq);
          }
        }
        if (nn == 0) { ss0 += ss; sq0 += sq; } else { ss1 += ss; sq1 += sq; }
      }
    }
  }

  __syncthreads();
  const int c2a = 16*(2*wh)     + ll;
  const int c2b = 16*(2*wh + 1) + ll;
  atomicAdd(&red[c2a], ss0);
  atomicAdd(&red[64 + c2a], sq0);
  atomicAdd(&red[c2b], ss1);
  atomicAdd(&red[64 + c2b], sq1);
  __syncthreads();
  if (tid < 64) {
    atomicAdd(&stats[128+tid], red[tid]);
    atomicAdd(&stats[192+tid], red[64+tid]);
  }
}

// ---------------------------------------------------------------------------
// K4: x2 = BN2(x2pre); outpre = x2 @ out_w^T + out_b; BN3 partials. (frozen)
// ---------------------------------------------------------------------------
__global__ __launch_bounds__(256) void k4_out(
    const float* __restrict__ x2pre, float* __restrict__ stats,
    const float* __restrict__ g2, const float* __restrict__ b2,
    const float* __restrict__ outw, const float* __restrict__ outb,
    float* __restrict__ outpre)
{
  extern __shared__ char smem[];
  u32* WTP = (u32*)smem;
  const int tid = threadIdx.x, wid = tid >> 6, lane = tid & 63;
  for (int t = tid; t < 2048; t += 256) {
    int cp = t >> 6, o = t & 63;
    WTP[t] = pkh(outw[o*64 + 2*cp], outw[o*64 + 2*cp + 1]);
  }
  __syncthreads();

  const float mean = stats[128+lane] * (1.f/NV);
  const float var  = stats[192+lane] * (1.f/NV) - mean*mean;
  const float sc   = rsqrtf(var + EPSB) * g2[lane];
  const float sh   = b2[lane] - mean * sc;
  const float obl  = outb[lane];
  float ssum = 0.f, ssq = 0.f;

  const int stride = gridDim.x << 4;
  for (int n0 = blockIdx.x*16 + wid*4; n0 < NV; n0 += stride) {
    float xa = x2pre[(size_t) n0   *64+lane] * sc + sh;
    float xb = x2pre[(size_t)(n0+1)*64+lane] * sc + sh;
    float xc = x2pre[(size_t)(n0+2)*64+lane] * sc + sh;
    float xd = x2pre[(size_t)(n0+3)*64+lane] * sc + sh;
    const u32 xpa = pkh(xa, __shfl_down(xa,1));
    const u32 xpb = pkh(xb, __shfl_down(xb,1));
    const u32 xpc = pkh(xc, __shfl_down(xc,1));
    const u32 xpd = pkh(xd, __shfl_down(xd,1));
    float a0 = obl, a1 = obl, a2 = obl, a3 = obl;
    #pragma unroll 8
    for (int cp = 0; cp < 32; ++cp) {
      u32 w = WTP[cp*64 + lane];
      a0 = fdot2(w, bcastu(xpa, 2*cp), a0);
      a1 = fdot2(w, bcastu(xpb, 2*cp), a1);
      a2 = fdot2(w, bcastu(xpc, 2*cp), a2);
      a3 = fdot2(w, bcastu(xpd, 2*cp), a3);
    }
    outpre[(size_t) n0   *64+lane] = a0;
    outpre[(size_t)(n0+1)*64+lane] = a1;
    outpre[(size_t)(n0+2)*64+lane] = a2;
    outpre[(size_t)(n0+3)*64+lane] = a3;
    ssum += (a0 + a1) + (a2 + a3);
    ssq = fmaf(a0,a0, fmaf(a1,a1, fmaf(a2,a2, fmaf(a3,a3, ssq))));
  }

  __syncthreads();
  float* red = (float*)smem;
  red[wid*64+lane] = ssum;
  red[256 + wid*64 + lane] = ssq;
  __syncthreads();
  if (wid == 0) {
    float t1 = 0.f, t2 = 0.f;
    #pragma unroll
    for (int w = 0; w < 4; ++w) { t1 += red[w*64+lane]; t2 += red[256+w*64+lane]; }
    atomicAdd(&stats[256+lane], t1);
    atomicAdd(&stats[320+lane], t2);
  }
}

// ---------------------------------------------------------------------------
// K5: out = relu(BN3(outpre))  (frozen)
// ---------------------------------------------------------------------------
__global__ __launch_bounds__(256) void k5_fin(
    const float* __restrict__ outpre, const float* __restrict__ stats,
    const float* __restrict__ g3, const float* __restrict__ b3,
    float* __restrict__ out)
{
  const int t = blockIdx.x*256 + threadIdx.x;
  const int c0 = (t*4) & 63;
  float sc[4], sh[4];
  #pragma unroll
  for (int j = 0; j < 4; ++j) {
    int c = c0 + j;
    float mean = stats[256+c] * (1.f/NV);
    float var  = stats[320+c] * (1.f/NV) - mean*mean;
    sc[j] = rsqrtf(var + EPSB) * g3[c];
    sh[j] = b3[c] - mean*sc[j];
  }
  for (int i = t; i < NV*16; i += 131072) {
    float4 v = *(const float4*)&outpre[(size_t)i*4];
    v.x = fmaxf(fmaf(v.x, sc[0], sh[0]), 0.f);
    v.y = fmaxf(fmaf(v.y, sc[1], sh[1]), 0.f);
    v.z = fmaxf(fmaf(v.z, sc[2], sh[2]), 0.f);
    v.w = fmaxf(fmaf(v.w, sc[3], sh[3]), 0.f);
    *(float4*)&out[(size_t)i*4] = v;
  }
}

extern "C" void kernel_launch(void* const* d_in, const int* in_sizes, int n_in,
                              void* d_out, int out_size, void* d_ws, size_t ws_size,
                              hipStream_t stream) {
  (void)in_sizes; (void)n_in; (void)out_size; (void)ws_size;
  const float* vf     = (const float*)d_in[0];
  const float* coords = (const float*)d_in[1];
  const int*   kidx   = (const int*)d_in[2];
  const void*  kmask  = d_in[3];
  const float* wq  = (const float*)d_in[4];  const float* bq  = (const float*)d_in[5];
  const float* wk  = (const float*)d_in[6];  /* bk cancels in softmax */
  const float* wv  = (const float*)d_in[8];  const float* bv  = (const float*)d_in[9];
  const float* wo  = (const float*)d_in[10]; const float* bo  = (const float*)d_in[11];
  const float* qpw = (const float*)d_in[12]; const float* qpb = (const float*)d_in[13];
  const float* kpw = (const float*)d_in[14]; const float* kpb = (const float*)d_in[15];
  const float* g1  = (const float*)d_in[16]; const float* b1  = (const float*)d_in[17];
  const float* g2  = (const float*)d_in[18]; const float* b2  = (const float*)d_in[19];
  const float* l1w = (const float*)d_in[20]; const float* l1b = (const float*)d_in[21];
  const float* l2w = (const float*)d_in[22]; const float* l2b = (const float*)d_in[23];
  const float* outw= (const float*)d_in[24]; const float* outb= (const float*)d_in[25];
  const float* g3  = (const float*)d_in[26]; const float* b3  = (const float*)d_in[27];

  float* wsf    = (float*)d_ws;
  float* x1pre  = wsf;                       // [N*64]
  float* x2pre  = wsf + (size_t)NV*64;       // [N*64]; aliases VP before K3
  u32*   VP     = (u32*)x2pre;               // packed (vf,P) f16 table, dead after K1
  float* outpre = x1pre;                     // alias: x1pre dead after K3
  float* stats  = wsf + (size_t)2*NV*64;     // [384]
  int*   mflag  = (int*)(stats + 384);

  (void)hipMemsetAsync(stats, 0, 384*sizeof(float), stream);

  (void)hipFuncSetAttribute((const void*)k1_attn, hipFuncAttributeMaxDynamicSharedMemorySize, 76288);
  (void)hipFuncSetAttribute((const void*)k3_mfma, hipFuncAttributeMaxDynamicSharedMemorySize, 110848);

  k0_detect<<<1, 256, 0, stream>>>((const u32*)kmask, mflag);
  k_prep<<<2048, 256, 0, stream>>>(vf, coords, kpw, VP);
  k1_attn<<<512, 512, 76288, stream>>>(vf, coords, kidx, kmask, mflag, VP,
      wq, bq, wk, wv, bv, wo, bo, qpw, qpb, kpb, x1pre, stats);
  k3_mfma<<<256, 512, 110848, stream>>>(x1pre, stats, g1, b1, l1w, l1b, l2w, l2b, x2pre);
  k4_out<<<1024, 256, 8192, stream>>>(x2pre, stats, g2, b2, outw, outb, outpre);
  k5_fin<<<512, 256, 0, stream>>>(outpre, stats, g3, b3, (float*)d_out);
}